// Round 1
// baseline (1451.897 us; speedup 1.0000x reference)
//
#include <hip/hip_runtime.h>
#include <math.h>

constexpr int Nn   = 50000;
constexpr int Ee   = 800000;
constexpr int Bb   = 128;
constexpr int INF  = 15;
constexpr int HID  = 256;
constexpr int OUTF = 128;

__device__ __forceinline__ float gelu_f(float v) {
    return 0.5f * v * (1.0f + erff(v * 0.7071067811865475f));
}

// ---------------- CSR build ----------------

__global__ void k_hist(const int* __restrict__ idx, int* __restrict__ cnt, int n) {
    int i = blockIdx.x * 256 + threadIdx.x;
    if (i < n) atomicAdd(&cnt[idx[i]], 1);
}

__global__ void k_scan_partial(const int* __restrict__ deg, int* __restrict__ partial, int n) {
    __shared__ int s[256];
    int tid = threadIdx.x;
    int i = blockIdx.x * 256 + tid;
    s[tid] = (i < n) ? deg[i] : 0;
    __syncthreads();
    for (int off = 128; off; off >>= 1) {
        if (tid < off) s[tid] += s[tid + off];
        __syncthreads();
    }
    if (tid == 0) partial[blockIdx.x] = s[0];
}

__global__ void k_scan_small(int* __restrict__ partial, int nb, int* __restrict__ offs_end, int total) {
    __shared__ int s[256];
    int tid = threadIdx.x;
    int v = (tid < nb) ? partial[tid] : 0;
    s[tid] = v;
    __syncthreads();
    for (int off = 1; off < 256; off <<= 1) {
        int t = (tid >= off) ? s[tid - off] : 0;
        __syncthreads();
        s[tid] += t;
        __syncthreads();
    }
    if (tid < nb) partial[tid] = s[tid] - v;   // exclusive prefix of block sums
    if (tid == 0) *offs_end = total;
}

__global__ void k_scan_final(const int* __restrict__ deg, const int* __restrict__ partial,
                             int* __restrict__ offs, int* __restrict__ cur,
                             float* __restrict__ invc, int n) {
    __shared__ int s[256];
    int tid = threadIdx.x;
    int i = blockIdx.x * 256 + tid;
    int v = (i < n) ? deg[i] : 0;
    s[tid] = v;
    __syncthreads();
    for (int off = 1; off < 256; off <<= 1) {
        int t = (tid >= off) ? s[tid - off] : 0;
        __syncthreads();
        s[tid] += t;
        __syncthreads();
    }
    int excl = s[tid] - v + partial[blockIdx.x];
    if (i < n) {
        offs[i] = excl;
        cur[i]  = excl;
        invc[i] = 1.0f / (float)(v > 1 ? v : 1);
    }
}

__global__ void k_scatter(const int* __restrict__ src, const int* __restrict__ dst,
                          int* __restrict__ cur, int* __restrict__ srcs, int n) {
    int e = blockIdx.x * 256 + threadIdx.x;
    if (e < n) {
        int d = dst[e];
        int p = atomicAdd(&cur[d], 1);
        srcs[p] = src[e];
    }
}

__global__ void k_bscan(const int* __restrict__ bcnt, int* __restrict__ boff) {
    __shared__ int s[128];
    int tid = threadIdx.x;
    int v = bcnt[tid];
    s[tid] = v;
    __syncthreads();
    for (int off = 1; off < 128; off <<= 1) {
        int t = (tid >= off) ? s[tid - off] : 0;
        __syncthreads();
        s[tid] += t;
        __syncthreads();
    }
    boff[tid] = s[tid] - v;
}

// ---------------- aggregation ----------------

// 15-dim: 16 lanes per node, 16 nodes per 256-thread block
__global__ void k_agg15(const float* __restrict__ x, const int* __restrict__ offs,
                        const int* __restrict__ srcs, const float* __restrict__ invc,
                        float* __restrict__ mean15) {
    int node = blockIdx.x * 16 + (threadIdx.x >> 4);
    int f = threadIdx.x & 15;
    int s0 = offs[node], s1 = offs[node + 1];
    float acc = 0.0f;
    for (int i = s0; i < s1; i++) {
        int s = srcs[i];
        if (f < 15) acc += x[s * INF + f];
    }
    if (f < 15) mean15[node * INF + f] = acc * invc[node];
}

// 256-dim: one 64-lane wave per node, float4 per lane
__global__ void k_agg256(const float* __restrict__ h, const int* __restrict__ offs,
                         const int* __restrict__ srcs, const float* __restrict__ invc,
                         float* __restrict__ mean) {
    int node = blockIdx.x * 4 + (threadIdx.x >> 6);
    int lane = threadIdx.x & 63;
    int s0 = offs[node], s1 = offs[node + 1];
    const float4* h4 = (const float4*)h;
    float ax = 0.f, ay = 0.f, az = 0.f, aw = 0.f;
    for (int i = s0; i < s1; i++) {
        int s = srcs[i];
        float4 v = h4[(size_t)s * 64 + lane];
        ax += v.x; ay += v.y; az += v.z; aw += v.w;
    }
    float ic = invc[node];
    float4 o; o.x = ax * ic; o.y = ay * ic; o.z = az * ic; o.w = aw * ic;
    ((float4*)mean)[(size_t)node * 64 + lane] = o;
}

// ---------------- layer 1 GEMM (K=15) + LN + GELU, one block per node ----------------

__global__ void k_gemm1(const float* __restrict__ mean15, const float* __restrict__ x,
                        const float* __restrict__ Wl, const float* __restrict__ Wr,
                        const float* __restrict__ bias, const float* __restrict__ g,
                        const float* __restrict__ bt, float* __restrict__ out) {
    int n = blockIdx.x;
    int j = threadIdx.x;
    __shared__ float sm[INF], sx[INF];
    __shared__ float red[8];
    if (j < 15) sm[j] = mean15[n * INF + j];
    else if (j >= 16 && j < 31) sx[j - 16] = x[n * INF + (j - 16)];
    __syncthreads();
    float acc = bias[j];
#pragma unroll
    for (int k = 0; k < INF; k++)
        acc += sm[k] * Wl[k * HID + j] + sx[k] * Wr[k * HID + j];
    float s1 = acc, s2 = acc * acc;
#pragma unroll
    for (int o = 32; o; o >>= 1) { s1 += __shfl_xor(s1, o); s2 += __shfl_xor(s2, o); }
    int wid = j >> 6, lane = j & 63;
    if (lane == 0) { red[wid] = s1; red[4 + wid] = s2; }
    __syncthreads();
    float ts1 = red[0] + red[1] + red[2] + red[3];
    float ts2 = red[4] + red[5] + red[6] + red[7];
    float mu = ts1 * (1.0f / HID);
    float var = ts2 * (1.0f / HID) - mu * mu;
    float rs = 1.0f / sqrtf(var + 1e-5f);
    float y = (acc - mu) * rs * g[j] + bt[j];
    out[(size_t)n * HID + j] = gelu_f(y);
}

// ---------------- big fused GEMM: C = mean@Wl + h@Wr + b, LN, GELU ----------------
// block = 256 threads, 64 nodes x NOUT cols. Thread (ng=tid>>5, cg=tid&31):
// rows ng*8..ng*8+7, cols cg + 32*i (strided -> conflict-free LDS b32 reads).

template <int NOUT>
__global__ __launch_bounds__(256) void k_gemm_big(
    const float* __restrict__ A0,   // mean [n][256]
    const float* __restrict__ A1,   // h    [n][256]
    const float* __restrict__ W0,   // Wl [256][NOUT]
    const float* __restrict__ W1,   // Wr [256][NOUT]
    const float* __restrict__ bias, const float* __restrict__ g,
    const float* __restrict__ bt, float* __restrict__ out, int n) {
    constexpr int KD = 256, KT = 16, MT = 64;
    constexpr int NC = NOUT / 32;
    __shared__ float As[KT * MT];
    __shared__ float Ws[KT * NOUT];
    int tid = threadIdx.x;
    int ng = tid >> 5, cg = tid & 31;
    int nb = blockIdx.x * MT;
    float C[8][NC] = {};

    for (int phase = 0; phase < 2; phase++) {
        const float* A = phase ? A1 : A0;
        const float* W = phase ? W1 : W0;
        for (int k0 = 0; k0 < KD; k0 += KT) {
            __syncthreads();
            {   // A tile: 64 x 16, stored transposed As[k][node]
                int r = tid >> 2, c = (tid & 3) * 4;
                int row = nb + r;
                float4 v = (row < n) ? *(const float4*)&A[(size_t)row * KD + k0 + c]
                                     : make_float4(0.f, 0.f, 0.f, 0.f);
                As[(c + 0) * MT + r] = v.x;
                As[(c + 1) * MT + r] = v.y;
                As[(c + 2) * MT + r] = v.z;
                As[(c + 3) * MT + r] = v.w;
            }
            {   // W tile: straight float4 copy of KT x NOUT
                const float4* Wg = (const float4*)&W[(size_t)k0 * NOUT];
                float4* Wsv = (float4*)Ws;
#pragma unroll
                for (int i = 0; i < KT * NOUT / 1024; i++)
                    Wsv[i * 256 + tid] = Wg[i * 256 + tid];
            }
            __syncthreads();
#pragma unroll
            for (int kk = 0; kk < KT; kk++) {
                const float4* ap = (const float4*)&As[kk * MT + ng * 8];
                float4 a0v = ap[0], a1v = ap[1];
                float a[8] = {a0v.x, a0v.y, a0v.z, a0v.w, a1v.x, a1v.y, a1v.z, a1v.w};
                float w[NC];
#pragma unroll
                for (int i = 0; i < NC; i++) w[i] = Ws[kk * NOUT + cg + 32 * i];
#pragma unroll
                for (int r = 0; r < 8; r++)
#pragma unroll
                    for (int i = 0; i < NC; i++)
                        C[r][i] = fmaf(a[r], w[i], C[r][i]);
            }
        }
    }

    float bv[NC], gv[NC], btv[NC];
#pragma unroll
    for (int i = 0; i < NC; i++) {
        int c = cg + 32 * i;
        bv[i] = bias[c]; gv[i] = g[c]; btv[i] = bt[c];
    }
#pragma unroll
    for (int r = 0; r < 8; r++) {
        int row = nb + ng * 8 + r;
        float s1 = 0.f, s2 = 0.f;
#pragma unroll
        for (int i = 0; i < NC; i++) {
            float v = C[r][i] + bv[i];
            C[r][i] = v;
            s1 += v; s2 += v * v;
        }
#pragma unroll
        for (int o = 16; o; o >>= 1) { s1 += __shfl_xor(s1, o); s2 += __shfl_xor(s2, o); }
        float mu = s1 * (1.0f / NOUT);
        float var = s2 * (1.0f / NOUT) - mu * mu;
        float rs = 1.0f / sqrtf(var + 1e-5f);
        if (row < n) {
#pragma unroll
            for (int i = 0; i < NC; i++) {
                float y = (C[r][i] - mu) * rs * gv[i] + btv[i];
                out[(size_t)row * NOUT + cg + 32 * i] = gelu_f(y);
            }
        }
    }
}

// ---------------- pool ----------------

__global__ void k_pool(const float* __restrict__ h4, const int* __restrict__ boff,
                       const int* __restrict__ bcnt, float* __restrict__ out) {
    int b = blockIdx.x, j = threadIdx.x;
    int s0 = boff[b], c = bcnt[b];
    float acc = 0.0f;
    for (int i = 0; i < c; i++) acc += h4[(size_t)(s0 + i) * OUTF + j];
    out[b * OUTF + j] = acc / fmaxf((float)c, 1.0f);
}

// ---------------- launch ----------------

extern "C" void kernel_launch(void* const* d_in, const int* in_sizes, int n_in,
                              void* d_out, int out_size, void* d_ws, size_t ws_size,
                              hipStream_t stream) {
    const float* x     = (const float*)d_in[0];
    const int*   ei    = (const int*)d_in[1];
    const int*   src   = ei;
    const int*   dst   = ei + Ee;
    const int*   batch = (const int*)d_in[2];
    const float* Wl1 = (const float*)d_in[3];
    const float* Wr1 = (const float*)d_in[4];
    const float* b1  = (const float*)d_in[5];
    const float* g1  = (const float*)d_in[6];
    const float* bt1 = (const float*)d_in[7];
    const float* Wl2 = (const float*)d_in[8];
    const float* Wr2 = (const float*)d_in[9];
    const float* b2  = (const float*)d_in[10];
    const float* g2  = (const float*)d_in[11];
    const float* bt2 = (const float*)d_in[12];
    const float* Wl3 = (const float*)d_in[13];
    const float* Wr3 = (const float*)d_in[14];
    const float* b3  = (const float*)d_in[15];
    const float* g3  = (const float*)d_in[16];
    const float* bt3 = (const float*)d_in[17];
    const float* Wl4 = (const float*)d_in[18];
    const float* Wr4 = (const float*)d_in[19];
    const float* b4  = (const float*)d_in[20];
    const float* g4  = (const float*)d_in[21];
    const float* bt4 = (const float*)d_in[22];
    float* out = (float*)d_out;

    char* ws = (char*)d_ws;
    size_t off = 0;
    auto alloc = [&](size_t bytes) -> char* {
        char* p = ws + off;
        off = (off + bytes + 255) & ~(size_t)255;
        return p;
    };
    int*   deg     = (int*)alloc((size_t)Nn * 4);
    int*   offs    = (int*)alloc((size_t)(Nn + 1) * 4);
    int*   cur     = (int*)alloc((size_t)Nn * 4);
    int*   srcs    = (int*)alloc((size_t)Ee * 4);
    float* invc    = (float*)alloc((size_t)Nn * 4);
    int*   bcnt    = (int*)alloc((size_t)Bb * 4);
    int*   boff    = (int*)alloc((size_t)Bb * 4);
    int*   partial = (int*)alloc(256 * 4);
    float* mean    = (float*)alloc((size_t)Nn * HID * 4);
    float* hA      = (float*)alloc((size_t)Nn * HID * 4);
    float* hB      = (float*)alloc((size_t)Nn * HID * 4);

    (void)hipMemsetAsync(deg, 0, (size_t)Nn * 4, stream);
    (void)hipMemsetAsync(bcnt, 0, (size_t)Bb * 4, stream);

    int nbScan = (Nn + 255) / 256;
    k_hist<<<(Ee + 255) / 256, 256, 0, stream>>>(dst, deg, Ee);
    k_hist<<<(Nn + 255) / 256, 256, 0, stream>>>(batch, bcnt, Nn);
    k_scan_partial<<<nbScan, 256, 0, stream>>>(deg, partial, Nn);
    k_scan_small<<<1, 256, 0, stream>>>(partial, nbScan, offs + Nn, Ee);
    k_scan_final<<<nbScan, 256, 0, stream>>>(deg, partial, offs, cur, invc, Nn);
    k_scatter<<<(Ee + 255) / 256, 256, 0, stream>>>(src, dst, cur, srcs, Ee);
    k_bscan<<<1, 128, 0, stream>>>(bcnt, boff);

    // layer 1
    k_agg15<<<Nn / 16, 256, 0, stream>>>(x, offs, srcs, invc, mean);
    k_gemm1<<<Nn, 256, 0, stream>>>(mean, x, Wl1, Wr1, b1, g1, bt1, hA);
    // layer 2
    k_agg256<<<Nn / 4, 256, 0, stream>>>(hA, offs, srcs, invc, mean);
    k_gemm_big<256><<<(Nn + 63) / 64, 256, 0, stream>>>(mean, hA, Wl2, Wr2, b2, g2, bt2, hB, Nn);
    // layer 3
    k_agg256<<<Nn / 4, 256, 0, stream>>>(hB, offs, srcs, invc, mean);
    k_gemm_big<256><<<(Nn + 63) / 64, 256, 0, stream>>>(mean, hB, Wl3, Wr3, b3, g3, bt3, hA, Nn);
    // layer 4
    k_agg256<<<Nn / 4, 256, 0, stream>>>(hA, offs, srcs, invc, mean);
    k_gemm_big<128><<<(Nn + 63) / 64, 256, 0, stream>>>(mean, hA, Wl4, Wr4, b4, g4, bt4, hB, Nn);
    // pool
    k_pool<<<Bb, 128, 0, stream>>>(hB, boff, bcnt, out);
}

// Round 2
// 1037.485 us; speedup vs baseline: 1.3994x; 1.3994x over previous
//
#include <hip/hip_runtime.h>
#include <math.h>

constexpr int Nn   = 50000;
constexpr int Ee   = 800000;
constexpr int Bb   = 128;
constexpr int INF  = 15;
constexpr int HID  = 256;
constexpr int OUTF = 128;

typedef __attribute__((ext_vector_type(8))) __bf16 bf16x8;
typedef __attribute__((ext_vector_type(4))) float  f32x4;

__device__ __forceinline__ float gelu_f(float v) {
    return 0.5f * v * (1.0f + erff(v * 0.7071067811865475f));
}

__device__ __forceinline__ unsigned short f2bf(float f) {
    union { float f; unsigned int u; } v; v.f = f;
    unsigned int r = v.u + 0x7fffu + ((v.u >> 16) & 1u);   // RNE
    return (unsigned short)(r >> 16);
}

__device__ __forceinline__ float bflo(unsigned int p) { return __uint_as_float(p << 16); }
__device__ __forceinline__ float bfhi(unsigned int p) { return __uint_as_float(p & 0xffff0000u); }

// ---------------- CSR build ----------------

__global__ void k_hist(const int* __restrict__ idx, int* __restrict__ cnt, int n) {
    int i = blockIdx.x * 256 + threadIdx.x;
    if (i < n) atomicAdd(&cnt[idx[i]], 1);
}

__global__ void k_scan_partial(const int* __restrict__ deg, int* __restrict__ partial, int n) {
    __shared__ int s[256];
    int tid = threadIdx.x;
    int i = blockIdx.x * 256 + tid;
    s[tid] = (i < n) ? deg[i] : 0;
    __syncthreads();
    for (int off = 128; off; off >>= 1) {
        if (tid < off) s[tid] += s[tid + off];
        __syncthreads();
    }
    if (tid == 0) partial[blockIdx.x] = s[0];
}

__global__ void k_scan_small(int* __restrict__ partial, int nb, int* __restrict__ offs_end, int total) {
    __shared__ int s[256];
    int tid = threadIdx.x;
    int v = (tid < nb) ? partial[tid] : 0;
    s[tid] = v;
    __syncthreads();
    for (int off = 1; off < 256; off <<= 1) {
        int t = (tid >= off) ? s[tid - off] : 0;
        __syncthreads();
        s[tid] += t;
        __syncthreads();
    }
    if (tid < nb) partial[tid] = s[tid] - v;
    if (tid == 0) *offs_end = total;
}

__global__ void k_scan_final(const int* __restrict__ deg, const int* __restrict__ partial,
                             int* __restrict__ offs, int* __restrict__ cur,
                             float* __restrict__ invc, int n) {
    __shared__ int s[256];
    int tid = threadIdx.x;
    int i = blockIdx.x * 256 + tid;
    int v = (i < n) ? deg[i] : 0;
    s[tid] = v;
    __syncthreads();
    for (int off = 1; off < 256; off <<= 1) {
        int t = (tid >= off) ? s[tid - off] : 0;
        __syncthreads();
        s[tid] += t;
        __syncthreads();
    }
    int excl = s[tid] - v + partial[blockIdx.x];
    if (i < n) {
        offs[i] = excl;
        cur[i]  = excl;
        invc[i] = 1.0f / (float)(v > 1 ? v : 1);
    }
}

__global__ void k_scatter(const int* __restrict__ src, const int* __restrict__ dst,
                          int* __restrict__ cur, int* __restrict__ srcs, int n) {
    int e = blockIdx.x * 256 + threadIdx.x;
    if (e < n) {
        int d = dst[e];
        int p = atomicAdd(&cur[d], 1);
        srcs[p] = src[e];
    }
}

__global__ void k_bscan(const int* __restrict__ bcnt, int* __restrict__ boff) {
    __shared__ int s[128];
    int tid = threadIdx.x;
    int v = bcnt[tid];
    s[tid] = v;
    __syncthreads();
    for (int off = 1; off < 128; off <<= 1) {
        int t = (tid >= off) ? s[tid - off] : 0;
        __syncthreads();
        s[tid] += t;
        __syncthreads();
    }
    boff[tid] = s[tid] - v;
}

// ---------------- weight prep: fp32 [Wl;Wr] -> fragment-ordered bf16 chunks ----------------
// chunk G = S*(2*NT*64) + (s*NT + T)*64 + lane holds 8 bf16:
//   W[k = S*64 + s*32 + (lane>>4)*8 + j][n = T*16 + (lane&15)], j=0..7
// where W[k][n] = (k<256) ? Wl[k][n] : Wr[k-256][n].

template <int NOUT>
__global__ void k_prepW(const float* __restrict__ Wl, const float* __restrict__ Wr,
                        uint4* __restrict__ outw) {
    constexpr int NT = NOUT / 16;
    int G = blockIdx.x * 256 + threadIdx.x;
    int per = 2 * NT * 64;
    int S = G / per, rem = G % per;
    int lane = rem & 63, sT = rem >> 6;
    int s = sT / NT, T = sT % NT;
    int q = lane >> 4, m = lane & 15;
    int k0 = S * 64 + s * 32 + q * 8;
    int nc = T * 16 + m;
    union { uint4 u; unsigned short h[8]; } pk;
#pragma unroll
    for (int j = 0; j < 8; j++) {
        int kk = k0 + j;
        float wv = (kk < 256) ? Wl[kk * NOUT + nc] : Wr[(kk - 256) * NOUT + nc];
        pk.h[j] = f2bf(wv);
    }
    outw[G] = pk.u;
}

// ---------------- aggregation ----------------

__global__ void k_agg15(const float* __restrict__ x, const int* __restrict__ offs,
                        const int* __restrict__ srcs, const float* __restrict__ invc,
                        float* __restrict__ mean15) {
    int node = blockIdx.x * 16 + (threadIdx.x >> 4);
    int f = threadIdx.x & 15;
    int s0 = offs[node], s1 = offs[node + 1];
    float acc = 0.0f;
    for (int i = s0; i < s1; i++) {
        int s = srcs[i];
        if (f < 15) acc += x[s * INF + f];
    }
    if (f < 15) mean15[node * INF + f] = acc * invc[node];
}

// bf16 rows: one wave per node, uint2 (4 bf16) per lane
__global__ void k_agg256_bf(const uint2* __restrict__ h2, const int* __restrict__ offs,
                            const int* __restrict__ srcs, const float* __restrict__ invc,
                            uint2* __restrict__ mean2) {
    int node = blockIdx.x * 4 + (threadIdx.x >> 6);
    int lane = threadIdx.x & 63;
    int s0 = offs[node], s1 = offs[node + 1];
    float a0 = 0.f, a1 = 0.f, a2 = 0.f, a3 = 0.f;
    for (int i = s0; i < s1; i++) {
        int s = srcs[i];
        uint2 v = h2[(size_t)s * 64 + lane];
        a0 += bflo(v.x); a1 += bfhi(v.x);
        a2 += bflo(v.y); a3 += bfhi(v.y);
    }
    float ic = invc[node];
    uint2 o;
    o.x = (unsigned int)f2bf(a0 * ic) | ((unsigned int)f2bf(a1 * ic) << 16);
    o.y = (unsigned int)f2bf(a2 * ic) | ((unsigned int)f2bf(a3 * ic) << 16);
    mean2[(size_t)node * 64 + lane] = o;
}

// ---------------- layer 1 GEMM (K=15) + LN + GELU, one block per node ----------------

__global__ void k_gemm1(const float* __restrict__ mean15, const float* __restrict__ x,
                        const float* __restrict__ Wl, const float* __restrict__ Wr,
                        const float* __restrict__ bias, const float* __restrict__ g,
                        const float* __restrict__ bt, unsigned short* __restrict__ out) {
    int n = blockIdx.x;
    int j = threadIdx.x;
    __shared__ float sm[INF], sx[INF];
    __shared__ float red[8];
    if (j < 15) sm[j] = mean15[n * INF + j];
    else if (j >= 16 && j < 31) sx[j - 16] = x[n * INF + (j - 16)];
    __syncthreads();
    float acc = bias[j];
#pragma unroll
    for (int k = 0; k < INF; k++)
        acc += sm[k] * Wl[k * HID + j] + sx[k] * Wr[k * HID + j];
    float s1 = acc, s2 = acc * acc;
#pragma unroll
    for (int o = 32; o; o >>= 1) { s1 += __shfl_xor(s1, o); s2 += __shfl_xor(s2, o); }
    int wid = j >> 6, lane = j & 63;
    if (lane == 0) { red[wid] = s1; red[4 + wid] = s2; }
    __syncthreads();
    float ts1 = red[0] + red[1] + red[2] + red[3];
    float ts2 = red[4] + red[5] + red[6] + red[7];
    float mu = ts1 * (1.0f / HID);
    float var = ts2 * (1.0f / HID) - mu * mu;
    float rs = 1.0f / sqrtf(var + 1e-5f);
    float y = (acc - mu) * rs * g[j] + bt[j];
    out[(size_t)n * HID + j] = f2bf(gelu_f(y));
}

// ---------------- MFMA GEMM: C = [mean|h] @ Wfrag + b, LN, GELU ----------------
// block: 256 threads = 4 waves, tile 64 rows x NOUT cols.
// wave w: all 64 rows x cols [w*CT*16, (w+1)*CT*16), 4x(CT) grid of 16x16 tiles.
// K = 512 as 8 stages of 64 (S<4 -> mean, S>=4 -> h), 2 MFMA K-steps (32) per stage.

template <int NOUT, bool F32OUT>
__global__ __launch_bounds__(256) void k_gemm_mfma(
    const unsigned short* __restrict__ Am,  // mean [n][256] bf16
    const unsigned short* __restrict__ Ah,  // h    [n][256] bf16
    const uint4* __restrict__ Wfrag,
    const float* __restrict__ bias, const float* __restrict__ g,
    const float* __restrict__ bt, void* __restrict__ outp, int n) {
    constexpr int NT  = NOUT / 16;   // col tiles in block
    constexpr int CT  = NT / 4;      // col tiles per wave
    constexpr int CPS = 2 * NT * 64; // uint4 chunks per K-stage
    __shared__ uint4 Bs[CPS];
    __shared__ float lnbuf[2][4][64];
    int tid = threadIdx.x;
    int w = tid >> 6, lane = tid & 63;
    int q = lane >> 4, m = lane & 15;
    int rowbase = blockIdx.x * 64;

    f32x4 acc[4][CT];
#pragma unroll
    for (int i = 0; i < 4; i++)
#pragma unroll
        for (int t = 0; t < CT; t++) acc[i][t] = (f32x4)0.f;

    union U { uint4 u; bf16x8 b; };

    for (int S = 0; S < 8; S++) {
        __syncthreads();
        for (int c = tid; c < CPS; c += 256) Bs[c] = Wfrag[S * CPS + c];
        __syncthreads();
        const unsigned short* A = (S < 4) ? Am : Ah;
        int kb = (S & 3) * 64;
#pragma unroll
        for (int s = 0; s < 2; s++) {
            int kk = kb + s * 32 + q * 8;
            U a[4];
#pragma unroll
            for (int i = 0; i < 4; i++) {
                int row = rowbase + i * 16 + m;
                a[i].u = (row < n) ? *(const uint4*)(A + (size_t)row * 256 + kk)
                                   : make_uint4(0u, 0u, 0u, 0u);
            }
            U b[CT];
#pragma unroll
            for (int t = 0; t < CT; t++)
                b[t].u = Bs[(s * NT + (w * CT + t)) * 64 + lane];
#pragma unroll
            for (int i = 0; i < 4; i++)
#pragma unroll
                for (int t = 0; t < CT; t++)
                    acc[i][t] = __builtin_amdgcn_mfma_f32_16x16x32_bf16(
                        a[i].b, b[t].b, acc[i][t], 0, 0, 0);
        }
    }

    // epilogue: bias + LN over NOUT cols + GELU
    int col0 = w * CT * 16;
    float bv[CT], gv[CT], btv[CT];
#pragma unroll
    for (int t = 0; t < CT; t++) {
        int c = col0 + t * 16 + m;
        bv[t] = bias[c]; gv[t] = g[c]; btv[t] = bt[c];
    }
    // per-(i,r): row = i*16 + q*4 + r; reduce s1,s2 over the 16 lanes of the quad
#pragma unroll
    for (int i = 0; i < 4; i++) {
#pragma unroll
        for (int r = 0; r < 4; r++) {
            float s1 = 0.f, s2 = 0.f;
#pragma unroll
            for (int t = 0; t < CT; t++) {
                float v = acc[i][t][r] + bv[t];
                acc[i][t][r] = v;
                s1 += v; s2 += v * v;
            }
#pragma unroll
            for (int o = 1; o < 16; o <<= 1) {
                s1 += __shfl_xor(s1, o);
                s2 += __shfl_xor(s2, o);
            }
            if (m == 0) {
                int row = i * 16 + q * 4 + r;
                lnbuf[0][w][row] = s1;
                lnbuf[1][w][row] = s2;
            }
        }
    }
    __syncthreads();
#pragma unroll
    for (int i = 0; i < 4; i++) {
#pragma unroll
        for (int r = 0; r < 4; r++) {
            int rit = i * 16 + q * 4 + r;
            float ts1 = lnbuf[0][0][rit] + lnbuf[0][1][rit] + lnbuf[0][2][rit] + lnbuf[0][3][rit];
            float ts2 = lnbuf[1][0][rit] + lnbuf[1][1][rit] + lnbuf[1][2][rit] + lnbuf[1][3][rit];
            float mu  = ts1 * (1.0f / NOUT);
            float var = ts2 * (1.0f / NOUT) - mu * mu;
            float rs  = 1.0f / sqrtf(var + 1e-5f);
            int row = rowbase + rit;
            if (row < n) {
#pragma unroll
                for (int t = 0; t < CT; t++) {
                    int c = col0 + t * 16 + m;
                    float y = (acc[i][t][r] - mu) * rs * gv[t] + btv[t];
                    float res = gelu_f(y);
                    if (F32OUT) ((float*)outp)[(size_t)row * NOUT + c] = res;
                    else ((unsigned short*)outp)[(size_t)row * NOUT + c] = f2bf(res);
                }
            }
        }
    }
}

// ---------------- pool ----------------

__global__ void k_pool(const float* __restrict__ h4, const int* __restrict__ boff,
                       const int* __restrict__ bcnt, float* __restrict__ out) {
    int b = blockIdx.x, j = threadIdx.x;
    int s0 = boff[b], c = bcnt[b];
    float acc = 0.0f;
    for (int i = 0; i < c; i++) acc += h4[(size_t)(s0 + i) * OUTF + j];
    out[b * OUTF + j] = acc / fmaxf((float)c, 1.0f);
}

// ---------------- launch ----------------

extern "C" void kernel_launch(void* const* d_in, const int* in_sizes, int n_in,
                              void* d_out, int out_size, void* d_ws, size_t ws_size,
                              hipStream_t stream) {
    const float* x     = (const float*)d_in[0];
    const int*   ei    = (const int*)d_in[1];
    const int*   src   = ei;
    const int*   dst   = ei + Ee;
    const int*   batch = (const int*)d_in[2];
    const float* Wl1 = (const float*)d_in[3];
    const float* Wr1 = (const float*)d_in[4];
    const float* b1  = (const float*)d_in[5];
    const float* g1  = (const float*)d_in[6];
    const float* bt1 = (const float*)d_in[7];
    const float* Wl2 = (const float*)d_in[8];
    const float* Wr2 = (const float*)d_in[9];
    const float* b2  = (const float*)d_in[10];
    const float* g2  = (const float*)d_in[11];
    const float* bt2 = (const float*)d_in[12];
    const float* Wl3 = (const float*)d_in[13];
    const float* Wr3 = (const float*)d_in[14];
    const float* b3  = (const float*)d_in[15];
    const float* g3  = (const float*)d_in[16];
    const float* bt3 = (const float*)d_in[17];
    const float* Wl4 = (const float*)d_in[18];
    const float* Wr4 = (const float*)d_in[19];
    const float* b4  = (const float*)d_in[20];
    const float* g4  = (const float*)d_in[21];
    const float* bt4 = (const float*)d_in[22];
    float* out = (float*)d_out;

    char* ws = (char*)d_ws;
    size_t off = 0;
    auto alloc = [&](size_t bytes) -> char* {
        char* p = ws + off;
        off = (off + bytes + 255) & ~(size_t)255;
        return p;
    };
    int*   deg     = (int*)alloc((size_t)Nn * 4);
    int*   offs    = (int*)alloc((size_t)(Nn + 1) * 4);
    int*   cur     = (int*)alloc((size_t)Nn * 4);
    int*   srcs    = (int*)alloc((size_t)Ee * 4);
    float* invc    = (float*)alloc((size_t)Nn * 4);
    int*   bcnt    = (int*)alloc((size_t)Bb * 4);
    int*   boff    = (int*)alloc((size_t)Bb * 4);
    int*   partial = (int*)alloc(256 * 4);
    float* mean15  = (float*)alloc((size_t)Nn * INF * 4);
    unsigned short* meanb = (unsigned short*)alloc((size_t)Nn * HID * 2);
    unsigned short* hA    = (unsigned short*)alloc((size_t)Nn * HID * 2);
    unsigned short* hB    = (unsigned short*)alloc((size_t)Nn * HID * 2);
    float* hOut    = (float*)alloc((size_t)Nn * OUTF * 4);
    uint4* W2f     = (uint4*)alloc((size_t)512 * HID * 2);
    uint4* W3f     = (uint4*)alloc((size_t)512 * HID * 2);
    uint4* W4f     = (uint4*)alloc((size_t)512 * OUTF * 2);

    (void)hipMemsetAsync(deg, 0, (size_t)Nn * 4, stream);
    (void)hipMemsetAsync(bcnt, 0, (size_t)Bb * 4, stream);

    int nbScan = (Nn + 255) / 256;
    k_hist<<<(Ee + 255) / 256, 256, 0, stream>>>(dst, deg, Ee);
    k_hist<<<(Nn + 255) / 256, 256, 0, stream>>>(batch, bcnt, Nn);
    k_scan_partial<<<nbScan, 256, 0, stream>>>(deg, partial, Nn);
    k_scan_small<<<1, 256, 0, stream>>>(partial, nbScan, offs + Nn, Ee);
    k_scan_final<<<nbScan, 256, 0, stream>>>(deg, partial, offs, cur, invc, Nn);
    k_scatter<<<(Ee + 255) / 256, 256, 0, stream>>>(src, dst, cur, srcs, Ee);
    k_bscan<<<1, 128, 0, stream>>>(bcnt, boff);

    // weight prep (fragment-ordered bf16)
    k_prepW<256><<<64, 256, 0, stream>>>(Wl2, Wr2, W2f);
    k_prepW<256><<<64, 256, 0, stream>>>(Wl3, Wr3, W3f);
    k_prepW<128><<<32, 256, 0, stream>>>(Wl4, Wr4, W4f);

    int gb = (Nn + 63) / 64;
    // layer 1
    k_agg15<<<Nn / 16, 256, 0, stream>>>(x, offs, srcs, invc, mean15);
    k_gemm1<<<Nn, 256, 0, stream>>>(mean15, x, Wl1, Wr1, b1, g1, bt1, hA);
    // layer 2
    k_agg256_bf<<<Nn / 4, 256, 0, stream>>>((const uint2*)hA, offs, srcs, invc, (uint2*)meanb);
    k_gemm_mfma<256, false><<<gb, 256, 0, stream>>>(meanb, hA, W2f, b2, g2, bt2, hB, Nn);
    // layer 3
    k_agg256_bf<<<Nn / 4, 256, 0, stream>>>((const uint2*)hB, offs, srcs, invc, (uint2*)meanb);
    k_gemm_mfma<256, false><<<gb, 256, 0, stream>>>(meanb, hB, W3f, b3, g3, bt3, hA, Nn);
    // layer 4
    k_agg256_bf<<<Nn / 4, 256, 0, stream>>>((const uint2*)hA, offs, srcs, invc, (uint2*)meanb);
    k_gemm_mfma<128, true><<<gb, 256, 0, stream>>>(meanb, hA, W4f, b4, g4, bt4, hOut, Nn);
    // pool
    k_pool<<<Bb, 128, 0, stream>>>(hOut, boff, bcnt, out);
}

// Round 3
// 769.658 us; speedup vs baseline: 1.8864x; 1.3480x over previous
//
#include <hip/hip_runtime.h>
#include <math.h>

constexpr int Nn   = 50000;
constexpr int Ee   = 800000;
constexpr int Bb   = 128;
constexpr int INF  = 15;
constexpr int HID  = 256;
constexpr int OUTF = 128;

constexpr int NCB   = (Nn + 255) / 256;   // 196 coarse buckets (dst>>8)
constexpr int CHUNK = 4096;
constexpr int NB1   = (Ee + CHUNK - 1) / CHUNK;  // 196 sort blocks
constexpr int SCANN = NCB * NB1;          // 38416

typedef __attribute__((ext_vector_type(8))) __bf16 bf16x8;
typedef __attribute__((ext_vector_type(4))) float  f32x4;

__device__ __forceinline__ float gelu_f(float v) {
    return 0.5f * v * (1.0f + erff(v * 0.7071067811865475f));
}

__device__ __forceinline__ unsigned short f2bf(float f) {
    union { float f; unsigned int u; } v; v.f = f;
    unsigned int r = v.u + 0x7fffu + ((v.u >> 16) & 1u);   // RNE
    return (unsigned short)(r >> 16);
}

__device__ __forceinline__ float bflo(unsigned int p) { return __uint_as_float(p << 16); }
__device__ __forceinline__ float bfhi(unsigned int p) { return __uint_as_float(p & 0xffff0000u); }

// ---------------- CSR build: two-level counting sort (LDS atomics only) ----------------

__global__ void k_sortA(const int* __restrict__ dst, int* __restrict__ Gcnt) {
    __shared__ int cnt[NCB];
    int tid = threadIdx.x, blk = blockIdx.x;
    for (int i = tid; i < NCB; i += 256) cnt[i] = 0;
    __syncthreads();
    int base = blk * CHUNK;
    for (int i = 0; i < CHUNK; i += 256) {
        int e = base + i + tid;
        if (e < Ee) atomicAdd(&cnt[dst[e] >> 8], 1);
    }
    __syncthreads();
    for (int i = tid; i < NCB; i += 256) Gcnt[i * NB1 + blk] = cnt[i];
}

// generic exclusive scan (3 kernels)
__global__ void k_gscan_partial(const int* __restrict__ in, int* __restrict__ partial, int n) {
    __shared__ int s[256];
    int tid = threadIdx.x, i = blockIdx.x * 256 + tid;
    s[tid] = (i < n) ? in[i] : 0;
    __syncthreads();
    for (int off = 128; off; off >>= 1) {
        if (tid < off) s[tid] += s[tid + off];
        __syncthreads();
    }
    if (tid == 0) partial[blockIdx.x] = s[0];
}

__global__ void k_gscan_mid(int* __restrict__ partial, int nb) {
    __shared__ int s[256];
    int tid = threadIdx.x;
    int v = (tid < nb) ? partial[tid] : 0;
    s[tid] = v;
    __syncthreads();
    for (int off = 1; off < 256; off <<= 1) {
        int t = (tid >= off) ? s[tid - off] : 0;
        __syncthreads();
        s[tid] += t;
        __syncthreads();
    }
    if (tid < nb) partial[tid] = s[tid] - v;
}

__global__ void k_gscan_final(const int* __restrict__ in, const int* __restrict__ partial,
                              int* __restrict__ out, int n) {
    __shared__ int s[256];
    int tid = threadIdx.x, i = blockIdx.x * 256 + tid;
    int v = (i < n) ? in[i] : 0;
    s[tid] = v;
    __syncthreads();
    for (int off = 1; off < 256; off <<= 1) {
        int t = (tid >= off) ? s[tid - off] : 0;
        __syncthreads();
        s[tid] += t;
        __syncthreads();
    }
    if (i < n) out[i] = s[tid] - v + partial[blockIdx.x];
}

__global__ void k_sortC(const int* __restrict__ dst, const int* __restrict__ srcv,
                        const int* __restrict__ Goff, unsigned int* __restrict__ pairs) {
    __shared__ int cur[NCB];
    int tid = threadIdx.x, blk = blockIdx.x;
    for (int i = tid; i < NCB; i += 256) cur[i] = Goff[i * NB1 + blk];
    __syncthreads();
    int base = blk * CHUNK;
    for (int i = 0; i < CHUNK; i += 256) {
        int e = base + i + tid;
        if (e < Ee) {
            int d = dst[e];
            int p = atomicAdd(&cur[d >> 8], 1);
            pairs[p] = ((unsigned int)(d & 255) << 16) | (unsigned int)srcv[e];
        }
    }
}

__global__ void k_sortD(const unsigned int* __restrict__ pairs, const int* __restrict__ Goff,
                        int* __restrict__ offs, int* __restrict__ srcs, float* __restrict__ invc) {
    __shared__ int fcnt[256];
    __shared__ int fbase[256];
    __shared__ int s[256];
    int tid = threadIdx.x, cb = blockIdx.x;
    int cbase = Goff[cb * NB1];
    int cend = (cb + 1 < NCB) ? Goff[(cb + 1) * NB1] : Ee;
    fcnt[tid] = 0;
    __syncthreads();
    for (int e = cbase + tid; e < cend; e += 256)
        atomicAdd(&fcnt[pairs[e] >> 16], 1);
    __syncthreads();
    int v = fcnt[tid];
    s[tid] = v;
    __syncthreads();
    for (int off = 1; off < 256; off <<= 1) {
        int t = (tid >= off) ? s[tid - off] : 0;
        __syncthreads();
        s[tid] += t;
        __syncthreads();
    }
    fbase[tid] = cbase + s[tid] - v;
    int node = cb * 256 + tid;
    if (node < Nn) {
        offs[node] = fbase[tid];
        invc[node] = 1.0f / (float)(v > 1 ? v : 1);
    }
    __syncthreads();
    fcnt[tid] = fbase[tid];   // cursors
    __syncthreads();
    for (int e = cbase + tid; e < cend; e += 256) {
        unsigned int pv = pairs[e];
        int p = atomicAdd(&fcnt[pv >> 16], 1);
        srcs[p] = (int)(pv & 0xFFFFu);
    }
}

// batch is sorted: binary-search the segment starts
__global__ void k_bsearch(const int* __restrict__ batch, int* __restrict__ boff,
                          int* __restrict__ offs) {
    int b = threadIdx.x;
    if (b <= Bb) {
        int lo = 0, hi = Nn;
        while (lo < hi) {
            int mid = (lo + hi) >> 1;
            if (batch[mid] < b) lo = mid + 1; else hi = mid;
        }
        boff[b] = lo;
    }
    if (b == 0) offs[Nn] = Ee;
}

// ---------------- weight prep: fp32 [Wl;Wr] -> fragment-ordered bf16 chunks ----------------

template <int NOUT>
__global__ void k_prepW(const float* __restrict__ Wl, const float* __restrict__ Wr,
                        uint4* __restrict__ outw) {
    constexpr int NT = NOUT / 16;
    int G = blockIdx.x * 256 + threadIdx.x;
    int per = 2 * NT * 64;
    int S = G / per, rem = G % per;
    int lane = rem & 63, sT = rem >> 6;
    int s = sT / NT, T = sT % NT;
    int q = lane >> 4, m = lane & 15;
    int k0 = S * 64 + s * 32 + q * 8;
    int nc = T * 16 + m;
    union { uint4 u; unsigned short h[8]; } pk;
#pragma unroll
    for (int j = 0; j < 8; j++) {
        int kk = k0 + j;
        float wv = (kk < 256) ? Wl[kk * NOUT + nc] : Wr[(kk - 256) * NOUT + nc];
        pk.h[j] = f2bf(wv);
    }
    outw[G] = pk.u;
}

// ---------------- aggregation ----------------

__global__ void k_agg15(const float* __restrict__ x, const int* __restrict__ offs,
                        const int* __restrict__ srcs, const float* __restrict__ invc,
                        float* __restrict__ mean15) {
    int node = blockIdx.x * 16 + (threadIdx.x >> 4);
    int f = threadIdx.x & 15;
    int s0 = offs[node], s1 = offs[node + 1];
    float acc = 0.0f;
    for (int i = s0; i < s1; i++) {
        int s = srcs[i];
        if (f < 15) acc += x[s * INF + f];
    }
    if (f < 15) mean15[node * INF + f] = acc * invc[node];
}

// bf16 rows: one wave per node, 2 edges per iteration, uint4 (8 bf16) per lane
__global__ void k_agg256_bf(const uint4* __restrict__ h4, const int* __restrict__ offs,
                            const int* __restrict__ srcs, const float* __restrict__ invc,
                            uint4* __restrict__ mean4) {
    int node = blockIdx.x * 4 + (threadIdx.x >> 6);
    int lane = threadIdx.x & 63;
    int sub = lane >> 5, q = lane & 31;
    int s0 = offs[node], s1 = offs[node + 1];
    float a[8] = {};
    int i = s0;
    for (; i + 1 < s1; i += 2) {
        int s = srcs[i + sub];
        uint4 v = h4[(size_t)s * 32 + q];
        a[0] += bflo(v.x); a[1] += bfhi(v.x);
        a[2] += bflo(v.y); a[3] += bfhi(v.y);
        a[4] += bflo(v.z); a[5] += bfhi(v.z);
        a[6] += bflo(v.w); a[7] += bfhi(v.w);
    }
    if (i < s1 && sub == 0) {
        int s = srcs[i];
        uint4 v = h4[(size_t)s * 32 + q];
        a[0] += bflo(v.x); a[1] += bfhi(v.x);
        a[2] += bflo(v.y); a[3] += bfhi(v.y);
        a[4] += bflo(v.z); a[5] += bfhi(v.z);
        a[6] += bflo(v.w); a[7] += bfhi(v.w);
    }
#pragma unroll
    for (int j = 0; j < 8; j++) a[j] += __shfl_xor(a[j], 32);
    if (sub == 0) {
        float ic = invc[node];
        uint4 o;
        o.x = (unsigned int)f2bf(a[0] * ic) | ((unsigned int)f2bf(a[1] * ic) << 16);
        o.y = (unsigned int)f2bf(a[2] * ic) | ((unsigned int)f2bf(a[3] * ic) << 16);
        o.z = (unsigned int)f2bf(a[4] * ic) | ((unsigned int)f2bf(a[5] * ic) << 16);
        o.w = (unsigned int)f2bf(a[6] * ic) | ((unsigned int)f2bf(a[7] * ic) << 16);
        mean4[(size_t)node * 32 + q] = o;
    }
}

// ---------------- layer 1 GEMM (K=15) + LN + GELU, one block per node ----------------

__global__ void k_gemm1(const float* __restrict__ mean15, const float* __restrict__ x,
                        const float* __restrict__ Wl, const float* __restrict__ Wr,
                        const float* __restrict__ bias, const float* __restrict__ g,
                        const float* __restrict__ bt, unsigned short* __restrict__ out) {
    int n = blockIdx.x;
    int j = threadIdx.x;
    __shared__ float sm[INF], sx[INF];
    __shared__ float red[8];
    if (j < 15) sm[j] = mean15[n * INF + j];
    else if (j >= 16 && j < 31) sx[j - 16] = x[n * INF + (j - 16)];
    __syncthreads();
    float acc = bias[j];
#pragma unroll
    for (int k = 0; k < INF; k++)
        acc += sm[k] * Wl[k * HID + j] + sx[k] * Wr[k * HID + j];
    float s1 = acc, s2 = acc * acc;
#pragma unroll
    for (int o = 32; o; o >>= 1) { s1 += __shfl_xor(s1, o); s2 += __shfl_xor(s2, o); }
    int wid = j >> 6, lane = j & 63;
    if (lane == 0) { red[wid] = s1; red[4 + wid] = s2; }
    __syncthreads();
    float ts1 = red[0] + red[1] + red[2] + red[3];
    float ts2 = red[4] + red[5] + red[6] + red[7];
    float mu = ts1 * (1.0f / HID);
    float var = ts2 * (1.0f / HID) - mu * mu;
    float rs = 1.0f / sqrtf(var + 1e-5f);
    float y = (acc - mu) * rs * g[j] + bt[j];
    out[(size_t)n * HID + j] = f2bf(gelu_f(y));
}

// ---------------- MFMA GEMM: C = [mean|h] @ Wfrag + b, LN, GELU ----------------

template <int NOUT, bool F32OUT>
__global__ __launch_bounds__(256) void k_gemm_mfma(
    const unsigned short* __restrict__ Am,  // mean [n][256] bf16
    const unsigned short* __restrict__ Ah,  // h    [n][256] bf16
    const uint4* __restrict__ Wfrag,
    const float* __restrict__ bias, const float* __restrict__ g,
    const float* __restrict__ bt, void* __restrict__ outp, int n) {
    constexpr int NT  = NOUT / 16;
    constexpr int CT  = NT / 4;
    constexpr int CPS = 2 * NT * 64;
    __shared__ uint4 Bs[CPS];
    __shared__ float lnbuf[2][4][64];
    int tid = threadIdx.x;
    int w = tid >> 6, lane = tid & 63;
    int q = lane >> 4, m = lane & 15;
    int rowbase = blockIdx.x * 64;

    f32x4 acc[4][CT];
#pragma unroll
    for (int i = 0; i < 4; i++)
#pragma unroll
        for (int t = 0; t < CT; t++) acc[i][t] = (f32x4)0.f;

    union U { uint4 u; bf16x8 b; };

    for (int S = 0; S < 8; S++) {
        __syncthreads();
        for (int c = tid; c < CPS; c += 256) Bs[c] = Wfrag[S * CPS + c];
        __syncthreads();
        const unsigned short* A = (S < 4) ? Am : Ah;
        int kb = (S & 3) * 64;
#pragma unroll
        for (int s = 0; s < 2; s++) {
            int kk = kb + s * 32 + q * 8;
            U a[4];
#pragma unroll
            for (int i = 0; i < 4; i++) {
                int row = rowbase + i * 16 + m;
                a[i].u = (row < n) ? *(const uint4*)(A + (size_t)row * 256 + kk)
                                   : make_uint4(0u, 0u, 0u, 0u);
            }
            U b[CT];
#pragma unroll
            for (int t = 0; t < CT; t++)
                b[t].u = Bs[(s * NT + (w * CT + t)) * 64 + lane];
#pragma unroll
            for (int i = 0; i < 4; i++)
#pragma unroll
                for (int t = 0; t < CT; t++)
                    acc[i][t] = __builtin_amdgcn_mfma_f32_16x16x32_bf16(
                        a[i].b, b[t].b, acc[i][t], 0, 0, 0);
        }
    }

    int col0 = w * CT * 16;
    float bv[CT], gv[CT], btv[CT];
#pragma unroll
    for (int t = 0; t < CT; t++) {
        int c = col0 + t * 16 + m;
        bv[t] = bias[c]; gv[t] = g[c]; btv[t] = bt[c];
    }
#pragma unroll
    for (int i = 0; i < 4; i++) {
#pragma unroll
        for (int r = 0; r < 4; r++) {
            float s1 = 0.f, s2 = 0.f;
#pragma unroll
            for (int t = 0; t < CT; t++) {
                float v = acc[i][t][r] + bv[t];
                acc[i][t][r] = v;
                s1 += v; s2 += v * v;
            }
#pragma unroll
            for (int o = 1; o < 16; o <<= 1) {
                s1 += __shfl_xor(s1, o);
                s2 += __shfl_xor(s2, o);
            }
            if (m == 0) {
                int row = i * 16 + q * 4 + r;
                lnbuf[0][w][row] = s1;
                lnbuf[1][w][row] = s2;
            }
        }
    }
    __syncthreads();
#pragma unroll
    for (int i = 0; i < 4; i++) {
#pragma unroll
        for (int r = 0; r < 4; r++) {
            int rit = i * 16 + q * 4 + r;
            float ts1 = lnbuf[0][0][rit] + lnbuf[0][1][rit] + lnbuf[0][2][rit] + lnbuf[0][3][rit];
            float ts2 = lnbuf[1][0][rit] + lnbuf[1][1][rit] + lnbuf[1][2][rit] + lnbuf[1][3][rit];
            float mu  = ts1 * (1.0f / NOUT);
            float var = ts2 * (1.0f / NOUT) - mu * mu;
            float rs  = 1.0f / sqrtf(var + 1e-5f);
            int row = rowbase + rit;
            if (row < n) {
#pragma unroll
                for (int t = 0; t < CT; t++) {
                    int c = col0 + t * 16 + m;
                    float y = (acc[i][t][r] - mu) * rs * gv[t] + btv[t];
                    float res = gelu_f(y);
                    if (F32OUT) ((float*)outp)[(size_t)row * NOUT + c] = res;
                    else ((unsigned short*)outp)[(size_t)row * NOUT + c] = f2bf(res);
                }
            }
        }
    }
}

// ---------------- pool ----------------

__global__ void k_pool(const float* __restrict__ h4, const int* __restrict__ boff,
                       float* __restrict__ out) {
    int b = blockIdx.x, j = threadIdx.x;
    int s0 = boff[b], c = boff[b + 1] - s0;
    float acc = 0.0f;
    for (int i = 0; i < c; i++) acc += h4[(size_t)(s0 + i) * OUTF + j];
    out[b * OUTF + j] = acc / fmaxf((float)c, 1.0f);
}

// ---------------- launch ----------------

extern "C" void kernel_launch(void* const* d_in, const int* in_sizes, int n_in,
                              void* d_out, int out_size, void* d_ws, size_t ws_size,
                              hipStream_t stream) {
    const float* x     = (const float*)d_in[0];
    const int*   ei    = (const int*)d_in[1];
    const int*   src   = ei;
    const int*   dst   = ei + Ee;
    const int*   batch = (const int*)d_in[2];
    const float* Wl1 = (const float*)d_in[3];
    const float* Wr1 = (const float*)d_in[4];
    const float* b1  = (const float*)d_in[5];
    const float* g1  = (const float*)d_in[6];
    const float* bt1 = (const float*)d_in[7];
    const float* Wl2 = (const float*)d_in[8];
    const float* Wr2 = (const float*)d_in[9];
    const float* b2  = (const float*)d_in[10];
    const float* g2  = (const float*)d_in[11];
    const float* bt2 = (const float*)d_in[12];
    const float* Wl3 = (const float*)d_in[13];
    const float* Wr3 = (const float*)d_in[14];
    const float* b3  = (const float*)d_in[15];
    const float* g3  = (const float*)d_in[16];
    const float* bt3 = (const float*)d_in[17];
    const float* Wl4 = (const float*)d_in[18];
    const float* Wr4 = (const float*)d_in[19];
    const float* b4  = (const float*)d_in[20];
    const float* g4  = (const float*)d_in[21];
    const float* bt4 = (const float*)d_in[22];
    float* out = (float*)d_out;

    char* ws = (char*)d_ws;
    size_t off = 0;
    auto alloc = [&](size_t bytes) -> char* {
        char* p = ws + off;
        off = (off + bytes + 255) & ~(size_t)255;
        return p;
    };
    int*   offs    = (int*)alloc((size_t)(Nn + 1) * 4);
    int*   srcs    = (int*)alloc((size_t)Ee * 4);
    float* invc    = (float*)alloc((size_t)Nn * 4);
    int*   boff    = (int*)alloc((size_t)(Bb + 1) * 4);
    unsigned int* pairs = (unsigned int*)alloc((size_t)Ee * 4);
    int*   Gcnt    = (int*)alloc((size_t)SCANN * 4);
    int*   Goff    = (int*)alloc((size_t)SCANN * 4);
    int*   partial = (int*)alloc(256 * 4);
    float* mean15  = (float*)alloc((size_t)Nn * INF * 4);
    unsigned short* meanb = (unsigned short*)alloc((size_t)Nn * HID * 2);
    unsigned short* hA    = (unsigned short*)alloc((size_t)Nn * HID * 2);
    unsigned short* hB    = (unsigned short*)alloc((size_t)Nn * HID * 2);
    float* hOut    = (float*)alloc((size_t)Nn * OUTF * 4);
    uint4* W2f     = (uint4*)alloc((size_t)512 * HID * 2);
    uint4* W3f     = (uint4*)alloc((size_t)512 * HID * 2);
    uint4* W4f     = (uint4*)alloc((size_t)512 * OUTF * 2);

    // CSR build (no global atomics)
    int nbScan = (SCANN + 255) / 256;
    k_sortA<<<NB1, 256, 0, stream>>>(dst, Gcnt);
    k_gscan_partial<<<nbScan, 256, 0, stream>>>(Gcnt, partial, SCANN);
    k_gscan_mid<<<1, 256, 0, stream>>>(partial, nbScan);
    k_gscan_final<<<nbScan, 256, 0, stream>>>(Gcnt, partial, Goff, SCANN);
    k_sortC<<<NB1, 256, 0, stream>>>(dst, src, Goff, pairs);
    k_sortD<<<NCB, 256, 0, stream>>>(pairs, Goff, offs, srcs, invc);
    k_bsearch<<<1, 256, 0, stream>>>(batch, boff, offs);

    // weight prep (fragment-ordered bf16)
    k_prepW<256><<<64, 256, 0, stream>>>(Wl2, Wr2, W2f);
    k_prepW<256><<<64, 256, 0, stream>>>(Wl3, Wr3, W3f);
    k_prepW<128><<<32, 256, 0, stream>>>(Wl4, Wr4, W4f);

    int gb = (Nn + 63) / 64;
    // layer 1
    k_agg15<<<Nn / 16, 256, 0, stream>>>(x, offs, srcs, invc, mean15);
    k_gemm1<<<Nn, 256, 0, stream>>>(mean15, x, Wl1, Wr1, b1, g1, bt1, hA);
    // layer 2
    k_agg256_bf<<<Nn / 4, 256, 0, stream>>>((const uint4*)hA, offs, srcs, invc, (uint4*)meanb);
    k_gemm_mfma<256, false><<<gb, 256, 0, stream>>>(meanb, hA, W2f, b2, g2, bt2, hB, Nn);
    // layer 3
    k_agg256_bf<<<Nn / 4, 256, 0, stream>>>((const uint4*)hB, offs, srcs, invc, (uint4*)meanb);
    k_gemm_mfma<256, false><<<gb, 256, 0, stream>>>(meanb, hB, W3f, b3, g3, bt3, hA, Nn);
    // layer 4
    k_agg256_bf<<<Nn / 4, 256, 0, stream>>>((const uint4*)hA, offs, srcs, invc, (uint4*)meanb);
    k_gemm_mfma<128, true><<<gb, 256, 0, stream>>>(meanb, hA, W4f, b4, g4, bt4, hOut, Nn);
    // pool
    k_pool<<<Bb, 128, 0, stream>>>(hOut, boff, out);
}

// Round 4
// 654.666 us; speedup vs baseline: 2.2178x; 1.1757x over previous
//
#include <hip/hip_runtime.h>
#include <math.h>

constexpr int Nn   = 50000;
constexpr int Ee   = 800000;
constexpr int Bb   = 128;
constexpr int INF  = 15;
constexpr int HID  = 256;
constexpr int OUTF = 128;

constexpr int NCB   = (Nn + 255) / 256;   // 196 coarse buckets (dst>>8)
constexpr int CHUNK = 4096;
constexpr int NB1   = (Ee + CHUNK - 1) / CHUNK;  // 196 sort blocks
constexpr int SCANN = NCB * NB1;          // 38416

typedef __attribute__((ext_vector_type(8))) __bf16 bf16x8;
typedef __attribute__((ext_vector_type(4))) float  f32x4;

__device__ __forceinline__ float gelu_f(float v) {
    return 0.5f * v * (1.0f + erff(v * 0.7071067811865475f));
}

__device__ __forceinline__ unsigned short f2bf(float f) {
    union { float f; unsigned int u; } v; v.f = f;
    unsigned int r = v.u + 0x7fffu + ((v.u >> 16) & 1u);   // RNE
    return (unsigned short)(r >> 16);
}

__device__ __forceinline__ float bflo(unsigned int p) { return __uint_as_float(p << 16); }
__device__ __forceinline__ float bfhi(unsigned int p) { return __uint_as_float(p & 0xffff0000u); }

// ---------------- CSR build: two-level counting sort (LDS atomics only) ----------------

__global__ void k_sortA(const int* __restrict__ dst, int* __restrict__ Gcnt) {
    __shared__ int cnt[NCB];
    int tid = threadIdx.x, blk = blockIdx.x;
    for (int i = tid; i < NCB; i += 256) cnt[i] = 0;
    __syncthreads();
    int base = blk * CHUNK;
    for (int i = 0; i < CHUNK; i += 256) {
        int e = base + i + tid;
        if (e < Ee) atomicAdd(&cnt[dst[e] >> 8], 1);
    }
    __syncthreads();
    for (int i = tid; i < NCB; i += 256) Gcnt[i * NB1 + blk] = cnt[i];
}

__global__ void k_gscan_partial(const int* __restrict__ in, int* __restrict__ partial, int n) {
    __shared__ int s[256];
    int tid = threadIdx.x, i = blockIdx.x * 256 + tid;
    s[tid] = (i < n) ? in[i] : 0;
    __syncthreads();
    for (int off = 128; off; off >>= 1) {
        if (tid < off) s[tid] += s[tid + off];
        __syncthreads();
    }
    if (tid == 0) partial[blockIdx.x] = s[0];
}

__global__ void k_gscan_mid(int* __restrict__ partial, int nb) {
    __shared__ int s[256];
    int tid = threadIdx.x;
    int v = (tid < nb) ? partial[tid] : 0;
    s[tid] = v;
    __syncthreads();
    for (int off = 1; off < 256; off <<= 1) {
        int t = (tid >= off) ? s[tid - off] : 0;
        __syncthreads();
        s[tid] += t;
        __syncthreads();
    }
    if (tid < nb) partial[tid] = s[tid] - v;
}

__global__ void k_gscan_final(const int* __restrict__ in, const int* __restrict__ partial,
                              int* __restrict__ out, int n) {
    __shared__ int s[256];
    int tid = threadIdx.x, i = blockIdx.x * 256 + tid;
    int v = (i < n) ? in[i] : 0;
    s[tid] = v;
    __syncthreads();
    for (int off = 1; off < 256; off <<= 1) {
        int t = (tid >= off) ? s[tid - off] : 0;
        __syncthreads();
        s[tid] += t;
        __syncthreads();
    }
    if (i < n) out[i] = s[tid] - v + partial[blockIdx.x];
}

__global__ void k_sortC(const int* __restrict__ dst, const int* __restrict__ srcv,
                        const int* __restrict__ Goff, unsigned int* __restrict__ pairs) {
    __shared__ int cur[NCB];
    int tid = threadIdx.x, blk = blockIdx.x;
    for (int i = tid; i < NCB; i += 256) cur[i] = Goff[i * NB1 + blk];
    __syncthreads();
    int base = blk * CHUNK;
    for (int i = 0; i < CHUNK; i += 256) {
        int e = base + i + tid;
        if (e < Ee) {
            int d = dst[e];
            int p = atomicAdd(&cur[d >> 8], 1);
            pairs[p] = ((unsigned int)(d & 255) << 16) | (unsigned int)srcv[e];
        }
    }
}

__global__ void k_sortD(const unsigned int* __restrict__ pairs, const int* __restrict__ Goff,
                        int* __restrict__ offs, int* __restrict__ srcs, float* __restrict__ invc) {
    __shared__ int fcnt[256];
    __shared__ int fbase[256];
    __shared__ int s[256];
    int tid = threadIdx.x, cb = blockIdx.x;
    int cbase = Goff[cb * NB1];
    int cend = (cb + 1 < NCB) ? Goff[(cb + 1) * NB1] : Ee;
    fcnt[tid] = 0;
    __syncthreads();
    for (int e = cbase + tid; e < cend; e += 256)
        atomicAdd(&fcnt[pairs[e] >> 16], 1);
    __syncthreads();
    int v = fcnt[tid];
    s[tid] = v;
    __syncthreads();
    for (int off = 1; off < 256; off <<= 1) {
        int t = (tid >= off) ? s[tid - off] : 0;
        __syncthreads();
        s[tid] += t;
        __syncthreads();
    }
    fbase[tid] = cbase + s[tid] - v;
    int node = cb * 256 + tid;
    if (node < Nn) {
        offs[node] = fbase[tid];
        invc[node] = 1.0f / (float)(v > 1 ? v : 1);
    }
    __syncthreads();
    fcnt[tid] = fbase[tid];
    __syncthreads();
    for (int e = cbase + tid; e < cend; e += 256) {
        unsigned int pv = pairs[e];
        int p = atomicAdd(&fcnt[pv >> 16], 1);
        srcs[p] = (int)(pv & 0xFFFFu);
    }
}

__global__ void k_bsearch(const int* __restrict__ batch, int* __restrict__ boff,
                          int* __restrict__ offs) {
    int b = threadIdx.x;
    if (b <= Bb) {
        int lo = 0, hi = Nn;
        while (lo < hi) {
            int mid = (lo + hi) >> 1;
            if (batch[mid] < b) lo = mid + 1; else hi = mid;
        }
        boff[b] = lo;
    }
    if (b == 0) offs[Nn] = Ee;
}

// ---------------- weight prep ----------------

template <int NOUT>
__global__ void k_prepW(const float* __restrict__ Wl, const float* __restrict__ Wr,
                        uint4* __restrict__ outw) {
    constexpr int NT = NOUT / 16;
    int G = blockIdx.x * 256 + threadIdx.x;
    int per = 2 * NT * 64;
    int S = G / per, rem = G % per;
    int lane = rem & 63, sT = rem >> 6;
    int s = sT / NT, T = sT % NT;
    int q = lane >> 4, m = lane & 15;
    int k0 = S * 64 + s * 32 + q * 8;
    int nc = T * 16 + m;
    union { uint4 u; unsigned short h[8]; } pk;
#pragma unroll
    for (int j = 0; j < 8; j++) {
        int kk = k0 + j;
        float wv = (kk < 256) ? Wl[kk * NOUT + nc] : Wr[(kk - 256) * NOUT + nc];
        pk.h[j] = f2bf(wv);
    }
    outw[G] = pk.u;
}

// ---------------- aggregation ----------------

__global__ void k_agg15(const float* __restrict__ x, const int* __restrict__ offs,
                        const int* __restrict__ srcs, const float* __restrict__ invc,
                        float* __restrict__ mean15) {
    int node = blockIdx.x * 16 + (threadIdx.x >> 4);
    int f = threadIdx.x & 15;
    int s0 = offs[node], s1 = offs[node + 1];
    float acc = 0.0f;
    for (int i = s0; i < s1; i++) {
        int s = srcs[i];
        if (f < 15) acc += x[s * INF + f];
    }
    if (f < 15) mean15[node * INF + f] = acc * invc[node];
}

// one wave per node; cooperative src-index staging (1 coalesced load for deg<=64),
// 4 edges in flight via shfl broadcast + 2x unroll of 2-edge groups.
__global__ void k_agg256_bf(const uint4* __restrict__ h4, const int* __restrict__ offs,
                            const int* __restrict__ srcs, const float* __restrict__ invc,
                            uint4* __restrict__ mean4) {
    int node = blockIdx.x * 4 + (threadIdx.x >> 6);
    int lane = threadIdx.x & 63;
    int sub = lane >> 5, q = lane & 31;
    int s0 = offs[node], s1 = offs[node + 1];
    int deg = s1 - s0;
    int dcap = deg < 64 ? deg : 64;
    int myidx = (lane < deg) ? srcs[s0 + lane] : 0;
    float a[8] = {};
    int i = 0;
    for (; i + 4 <= dcap; i += 4) {
        int sA = __shfl(myidx, i + sub);
        int sB = __shfl(myidx, i + 2 + sub);
        uint4 vA = h4[(size_t)sA * 32 + q];
        uint4 vB = h4[(size_t)sB * 32 + q];
        a[0] += bflo(vA.x); a[1] += bfhi(vA.x);
        a[2] += bflo(vA.y); a[3] += bfhi(vA.y);
        a[4] += bflo(vA.z); a[5] += bfhi(vA.z);
        a[6] += bflo(vA.w); a[7] += bfhi(vA.w);
        a[0] += bflo(vB.x); a[1] += bfhi(vB.x);
        a[2] += bflo(vB.y); a[3] += bfhi(vB.y);
        a[4] += bflo(vB.z); a[5] += bfhi(vB.z);
        a[6] += bflo(vB.w); a[7] += bfhi(vB.w);
    }
    if (i + 2 <= dcap) {
        int sA = __shfl(myidx, i + sub);
        uint4 vA = h4[(size_t)sA * 32 + q];
        a[0] += bflo(vA.x); a[1] += bfhi(vA.x);
        a[2] += bflo(vA.y); a[3] += bfhi(vA.y);
        a[4] += bflo(vA.z); a[5] += bfhi(vA.z);
        a[6] += bflo(vA.w); a[7] += bfhi(vA.w);
        i += 2;
    }
    if (i < dcap && sub == 0) {
        int sA = __shfl(myidx, i);
        uint4 vA = h4[(size_t)sA * 32 + q];
        a[0] += bflo(vA.x); a[1] += bfhi(vA.x);
        a[2] += bflo(vA.y); a[3] += bfhi(vA.y);
        a[4] += bflo(vA.z); a[5] += bfhi(vA.z);
        a[6] += bflo(vA.w); a[7] += bfhi(vA.w);
    }
    // rare overflow: deg > 64
    for (int j = 64; j + 1 < deg; j += 2) {
        int s = srcs[s0 + j + sub];
        uint4 v = h4[(size_t)s * 32 + q];
        a[0] += bflo(v.x); a[1] += bfhi(v.x);
        a[2] += bflo(v.y); a[3] += bfhi(v.y);
        a[4] += bflo(v.z); a[5] += bfhi(v.z);
        a[6] += bflo(v.w); a[7] += bfhi(v.w);
    }
    if (deg > 64 && !((deg - 64) & 1) == false && sub == 0) {
        // (deg-64) odd -> one leftover edge at s1-1
        int s = srcs[s1 - 1];
        uint4 v = h4[(size_t)s * 32 + q];
        a[0] += bflo(v.x); a[1] += bfhi(v.x);
        a[2] += bflo(v.y); a[3] += bfhi(v.y);
        a[4] += bflo(v.z); a[5] += bfhi(v.z);
        a[6] += bflo(v.w); a[7] += bfhi(v.w);
    }
#pragma unroll
    for (int j = 0; j < 8; j++) a[j] += __shfl_xor(a[j], 32);
    if (sub == 0) {
        float ic = invc[node];
        uint4 o;
        o.x = (unsigned int)f2bf(a[0] * ic) | ((unsigned int)f2bf(a[1] * ic) << 16);
        o.y = (unsigned int)f2bf(a[2] * ic) | ((unsigned int)f2bf(a[3] * ic) << 16);
        o.z = (unsigned int)f2bf(a[4] * ic) | ((unsigned int)f2bf(a[5] * ic) << 16);
        o.w = (unsigned int)f2bf(a[6] * ic) | ((unsigned int)f2bf(a[7] * ic) << 16);
        mean4[(size_t)node * 32 + q] = o;
    }
}

// ---------------- layer 1 GEMM (K=15) + LN + GELU ----------------

__global__ void k_gemm1(const float* __restrict__ mean15, const float* __restrict__ x,
                        const float* __restrict__ Wl, const float* __restrict__ Wr,
                        const float* __restrict__ bias, const float* __restrict__ g,
                        const float* __restrict__ bt, unsigned short* __restrict__ out) {
    int n = blockIdx.x;
    int j = threadIdx.x;
    __shared__ float sm[INF], sx[INF];
    __shared__ float red[8];
    if (j < 15) sm[j] = mean15[n * INF + j];
    else if (j >= 16 && j < 31) sx[j - 16] = x[n * INF + (j - 16)];
    __syncthreads();
    float acc = bias[j];
#pragma unroll
    for (int k = 0; k < INF; k++)
        acc += sm[k] * Wl[k * HID + j] + sx[k] * Wr[k * HID + j];
    float s1 = acc, s2 = acc * acc;
#pragma unroll
    for (int o = 32; o; o >>= 1) { s1 += __shfl_xor(s1, o); s2 += __shfl_xor(s2, o); }
    int wid = j >> 6, lane = j & 63;
    if (lane == 0) { red[wid] = s1; red[4 + wid] = s2; }
    __syncthreads();
    float ts1 = red[0] + red[1] + red[2] + red[3];
    float ts2 = red[4] + red[5] + red[6] + red[7];
    float mu = ts1 * (1.0f / HID);
    float var = ts2 * (1.0f / HID) - mu * mu;
    float rs = 1.0f / sqrtf(var + 1e-5f);
    float y = (acc - mu) * rs * g[j] + bt[j];
    out[(size_t)n * HID + j] = f2bf(gelu_f(y));
}

// ---------------- MFMA GEMM: C = [mean|h] @ Wfrag + b, LN, GELU ----------------

template <int NOUT, bool F32OUT>
__global__ __launch_bounds__(256) void k_gemm_mfma(
    const unsigned short* __restrict__ Am,
    const unsigned short* __restrict__ Ah,
    const uint4* __restrict__ Wfrag,
    const float* __restrict__ bias, const float* __restrict__ g,
    const float* __restrict__ bt, void* __restrict__ outp, int n) {
    constexpr int NT  = NOUT / 16;
    constexpr int CT  = NT / 4;
    constexpr int CPS = 2 * NT * 64;
    __shared__ uint4 Bs[CPS];
    __shared__ float lnbuf[2][4][64];
    int tid = threadIdx.x;
    int w = tid >> 6, lane = tid & 63;
    int q = lane >> 4, m = lane & 15;
    int rowbase = blockIdx.x * 64;

    f32x4 acc[4][CT];
#pragma unroll
    for (int i = 0; i < 4; i++)
#pragma unroll
        for (int t = 0; t < CT; t++) acc[i][t] = (f32x4)0.f;

    union U { uint4 u; bf16x8 b; };

    for (int S = 0; S < 8; S++) {
        __syncthreads();
        for (int c = tid; c < CPS; c += 256) Bs[c] = Wfrag[S * CPS + c];
        __syncthreads();
        const unsigned short* A = (S < 4) ? Am : Ah;
        int kb = (S & 3) * 64;
#pragma unroll
        for (int s = 0; s < 2; s++) {
            int kk = kb + s * 32 + q * 8;
            U a[4];
#pragma unroll
            for (int i = 0; i < 4; i++) {
                int row = rowbase + i * 16 + m;
                a[i].u = (row < n) ? *(const uint4*)(A + (size_t)row * 256 + kk)
                                   : make_uint4(0u, 0u, 0u, 0u);
            }
            U b[CT];
#pragma unroll
            for (int t = 0; t < CT; t++)
                b[t].u = Bs[(s * NT + (w * CT + t)) * 64 + lane];
#pragma unroll
            for (int i = 0; i < 4; i++)
#pragma unroll
                for (int t = 0; t < CT; t++)
                    acc[i][t] = __builtin_amdgcn_mfma_f32_16x16x32_bf16(
                        a[i].b, b[t].b, acc[i][t], 0, 0, 0);
        }
    }

    int col0 = w * CT * 16;
    float bv[CT], gv[CT], btv[CT];
#pragma unroll
    for (int t = 0; t < CT; t++) {
        int c = col0 + t * 16 + m;
        bv[t] = bias[c]; gv[t] = g[c]; btv[t] = bt[c];
    }
#pragma unroll
    for (int i = 0; i < 4; i++) {
#pragma unroll
        for (int r = 0; r < 4; r++) {
            float s1 = 0.f, s2 = 0.f;
#pragma unroll
            for (int t = 0; t < CT; t++) {
                float v = acc[i][t][r] + bv[t];
                acc[i][t][r] = v;
                s1 += v; s2 += v * v;
            }
#pragma unroll
            for (int o = 1; o < 16; o <<= 1) {
                s1 += __shfl_xor(s1, o);
                s2 += __shfl_xor(s2, o);
            }
            if (m == 0) {
                int row = i * 16 + q * 4 + r;
                lnbuf[0][w][row] = s1;
                lnbuf[1][w][row] = s2;
            }
        }
    }
    __syncthreads();
#pragma unroll
    for (int i = 0; i < 4; i++) {
#pragma unroll
        for (int r = 0; r < 4; r++) {
            int rit = i * 16 + q * 4 + r;
            float ts1 = lnbuf[0][0][rit] + lnbuf[0][1][rit] + lnbuf[0][2][rit] + lnbuf[0][3][rit];
            float ts2 = lnbuf[1][0][rit] + lnbuf[1][1][rit] + lnbuf[1][2][rit] + lnbuf[1][3][rit];
            float mu  = ts1 * (1.0f / NOUT);
            float var = ts2 * (1.0f / NOUT) - mu * mu;
            float rs  = 1.0f / sqrtf(var + 1e-5f);
            int row = rowbase + rit;
            if (row < n) {
#pragma unroll
                for (int t = 0; t < CT; t++) {
                    int c = col0 + t * 16 + m;
                    float y = (acc[i][t][r] - mu) * rs * gv[t] + btv[t];
                    float res = gelu_f(y);
                    if (F32OUT) ((float*)outp)[(size_t)row * NOUT + c] = res;
                    else ((unsigned short*)outp)[(size_t)row * NOUT + c] = f2bf(res);
                }
            }
        }
    }
}

// ---------------- pool: 8 row-groups x 128 features, 4x unroll ----------------

__global__ __launch_bounds__(1024) void k_pool(const float* __restrict__ h,
                                               const int* __restrict__ boff,
                                               float* __restrict__ out) {
    __shared__ float red[8][128];
    int b = blockIdx.x, tid = threadIdx.x;
    int j = tid & 127, grp = tid >> 7;
    int s0 = boff[b], s1 = boff[b + 1];
    float a0 = 0.f, a1 = 0.f, a2 = 0.f, a3 = 0.f;
    int i = s0 + grp;
    for (; i + 24 < s1; i += 32) {
        a0 += h[(size_t)i * OUTF + j];
        a1 += h[(size_t)(i + 8) * OUTF + j];
        a2 += h[(size_t)(i + 16) * OUTF + j];
        a3 += h[(size_t)(i + 24) * OUTF + j];
    }
    for (; i < s1; i += 8) a0 += h[(size_t)i * OUTF + j];
    red[grp][j] = (a0 + a1) + (a2 + a3);
    __syncthreads();
    if (tid < 128) {
        float s = ((red[0][tid] + red[1][tid]) + (red[2][tid] + red[3][tid]))
                + ((red[4][tid] + red[5][tid]) + (red[6][tid] + red[7][tid]));
        int c = s1 - s0;
        out[b * OUTF + tid] = s / fmaxf((float)c, 1.0f);
    }
}

// ---------------- launch ----------------

extern "C" void kernel_launch(void* const* d_in, const int* in_sizes, int n_in,
                              void* d_out, int out_size, void* d_ws, size_t ws_size,
                              hipStream_t stream) {
    const float* x     = (const float*)d_in[0];
    const int*   ei    = (const int*)d_in[1];
    const int*   src   = ei;
    const int*   dst   = ei + Ee;
    const int*   batch = (const int*)d_in[2];
    const float* Wl1 = (const float*)d_in[3];
    const float* Wr1 = (const float*)d_in[4];
    const float* b1  = (const float*)d_in[5];
    const float* g1  = (const float*)d_in[6];
    const float* bt1 = (const float*)d_in[7];
    const float* Wl2 = (const float*)d_in[8];
    const float* Wr2 = (const float*)d_in[9];
    const float* b2  = (const float*)d_in[10];
    const float* g2  = (const float*)d_in[11];
    const float* bt2 = (const float*)d_in[12];
    const float* Wl3 = (const float*)d_in[13];
    const float* Wr3 = (const float*)d_in[14];
    const float* b3  = (const float*)d_in[15];
    const float* g3  = (const float*)d_in[16];
    const float* bt3 = (const float*)d_in[17];
    const float* Wl4 = (const float*)d_in[18];
    const float* Wr4 = (const float*)d_in[19];
    const float* b4  = (const float*)d_in[20];
    const float* g4  = (const float*)d_in[21];
    const float* bt4 = (const float*)d_in[22];
    float* out = (float*)d_out;

    char* ws = (char*)d_ws;
    size_t off = 0;
    auto alloc = [&](size_t bytes) -> char* {
        char* p = ws + off;
        off = (off + bytes + 255) & ~(size_t)255;
        return p;
    };
    int*   offs    = (int*)alloc((size_t)(Nn + 1) * 4);
    int*   srcs    = (int*)alloc((size_t)Ee * 4);
    float* invc    = (float*)alloc((size_t)Nn * 4);
    int*   boff    = (int*)alloc((size_t)(Bb + 1) * 4);
    unsigned int* pairs = (unsigned int*)alloc((size_t)Ee * 4);
    int*   Gcnt    = (int*)alloc((size_t)SCANN * 4);
    int*   Goff    = (int*)alloc((size_t)SCANN * 4);
    int*   partial = (int*)alloc(256 * 4);
    float* mean15  = (float*)alloc((size_t)Nn * INF * 4);
    unsigned short* meanb = (unsigned short*)alloc((size_t)Nn * HID * 2);
    unsigned short* hA    = (unsigned short*)alloc((size_t)Nn * HID * 2);
    unsigned short* hB    = (unsigned short*)alloc((size_t)Nn * HID * 2);
    float* hOut    = (float*)alloc((size_t)Nn * OUTF * 4);
    uint4* W2f     = (uint4*)alloc((size_t)512 * HID * 2);
    uint4* W3f     = (uint4*)alloc((size_t)512 * HID * 2);
    uint4* W4f     = (uint4*)alloc((size_t)512 * OUTF * 2);

    int nbScan = (SCANN + 255) / 256;
    k_sortA<<<NB1, 256, 0, stream>>>(dst, Gcnt);
    k_gscan_partial<<<nbScan, 256, 0, stream>>>(Gcnt, partial, SCANN);
    k_gscan_mid<<<1, 256, 0, stream>>>(partial, nbScan);
    k_gscan_final<<<nbScan, 256, 0, stream>>>(Gcnt, partial, Goff, SCANN);
    k_sortC<<<NB1, 256, 0, stream>>>(dst, src, Goff, pairs);
    k_sortD<<<NCB, 256, 0, stream>>>(pairs, Goff, offs, srcs, invc);
    k_bsearch<<<1, 256, 0, stream>>>(batch, boff, offs);

    k_prepW<256><<<64, 256, 0, stream>>>(Wl2, Wr2, W2f);
    k_prepW<256><<<64, 256, 0, stream>>>(Wl3, Wr3, W3f);
    k_prepW<128><<<32, 256, 0, stream>>>(Wl4, Wr4, W4f);

    int gb = (Nn + 63) / 64;
    // layer 1
    k_agg15<<<Nn / 16, 256, 0, stream>>>(x, offs, srcs, invc, mean15);
    k_gemm1<<<Nn, 256, 0, stream>>>(mean15, x, Wl1, Wr1, b1, g1, bt1, hA);
    // layer 2
    k_agg256_bf<<<Nn / 4, 256, 0, stream>>>((const uint4*)hA, offs, srcs, invc, (uint4*)meanb);
    k_gemm_mfma<256, false><<<gb, 256, 0, stream>>>(meanb, hA, W2f, b2, g2, bt2, hB, Nn);
    // layer 3
    k_agg256_bf<<<Nn / 4, 256, 0, stream>>>((const uint4*)hB, offs, srcs, invc, (uint4*)meanb);
    k_gemm_mfma<256, false><<<gb, 256, 0, stream>>>(meanb, hB, W3f, b3, g3, bt3, hA, Nn);
    // layer 4
    k_agg256_bf<<<Nn / 4, 256, 0, stream>>>((const uint4*)hA, offs, srcs, invc, (uint4*)meanb);
    k_gemm_mfma<128, true><<<gb, 256, 0, stream>>>(meanb, hA, W4f, b4, g4, bt4, hOut, Nn);
    // pool
    k_pool<<<Bb, 1024, 0, stream>>>(hOut, boff, out);
}

// Round 5
// 590.208 us; speedup vs baseline: 2.4600x; 1.1092x over previous
//
#include <hip/hip_runtime.h>
#include <math.h>

constexpr int Nn   = 50000;
constexpr int Ee   = 800000;
constexpr int Bb   = 128;
constexpr int INF  = 15;
constexpr int HID  = 256;
constexpr int OUTF = 128;

constexpr int NCB   = (Nn + 255) / 256;   // 196 coarse buckets (dst>>8)
constexpr int CHUNK = 4096;
constexpr int NB1   = (Ee + CHUNK - 1) / CHUNK;  // 196 sort blocks
constexpr int SCANN = NCB * NB1;          // 38416

typedef __attribute__((ext_vector_type(8))) __bf16 bf16x8;
typedef __attribute__((ext_vector_type(4))) float  f32x4;

__device__ __forceinline__ float gelu_f(float v) {
    return 0.5f * v * (1.0f + erff(v * 0.7071067811865475f));
}

__device__ __forceinline__ unsigned short f2bf(float f) {
    union { float f; unsigned int u; } v; v.f = f;
    unsigned int r = v.u + 0x7fffu + ((v.u >> 16) & 1u);   // RNE
    return (unsigned short)(r >> 16);
}

__device__ __forceinline__ float bflo(unsigned int p) { return __uint_as_float(p << 16); }
__device__ __forceinline__ float bfhi(unsigned int p) { return __uint_as_float(p & 0xffff0000u); }

// ---------------- CSR build: two-level counting sort (LDS atomics only) ----------------

__global__ void k_sortA(const int* __restrict__ dst, int* __restrict__ Gcnt) {
    __shared__ int cnt[NCB];
    int tid = threadIdx.x, blk = blockIdx.x;
    for (int i = tid; i < NCB; i += 256) cnt[i] = 0;
    __syncthreads();
    int base = blk * CHUNK;
    for (int i = 0; i < CHUNK; i += 256) {
        int e = base + i + tid;
        if (e < Ee) atomicAdd(&cnt[dst[e] >> 8], 1);
    }
    __syncthreads();
    for (int i = tid; i < NCB; i += 256) Gcnt[i * NB1 + blk] = cnt[i];
}

__global__ void k_gscan_partial(const int* __restrict__ in, int* __restrict__ partial, int n) {
    __shared__ int s[256];
    int tid = threadIdx.x, i = blockIdx.x * 256 + tid;
    s[tid] = (i < n) ? in[i] : 0;
    __syncthreads();
    for (int off = 128; off; off >>= 1) {
        if (tid < off) s[tid] += s[tid + off];
        __syncthreads();
    }
    if (tid == 0) partial[blockIdx.x] = s[0];
}

__global__ void k_gscan_mid(int* __restrict__ partial, int nb) {
    __shared__ int s[256];
    int tid = threadIdx.x;
    int v = (tid < nb) ? partial[tid] : 0;
    s[tid] = v;
    __syncthreads();
    for (int off = 1; off < 256; off <<= 1) {
        int t = (tid >= off) ? s[tid - off] : 0;
        __syncthreads();
        s[tid] += t;
        __syncthreads();
    }
    if (tid < nb) partial[tid] = s[tid] - v;
}

__global__ void k_gscan_final(const int* __restrict__ in, const int* __restrict__ partial,
                              int* __restrict__ out, int n) {
    __shared__ int s[256];
    int tid = threadIdx.x, i = blockIdx.x * 256 + tid;
    int v = (i < n) ? in[i] : 0;
    s[tid] = v;
    __syncthreads();
    for (int off = 1; off < 256; off <<= 1) {
        int t = (tid >= off) ? s[tid - off] : 0;
        __syncthreads();
        s[tid] += t;
        __syncthreads();
    }
    if (i < n) out[i] = s[tid] - v + partial[blockIdx.x];
}

__global__ void k_sortC(const int* __restrict__ dst, const int* __restrict__ srcv,
                        const int* __restrict__ Goff, unsigned int* __restrict__ pairs) {
    __shared__ int cur[NCB];
    int tid = threadIdx.x, blk = blockIdx.x;
    for (int i = tid; i < NCB; i += 256) cur[i] = Goff[i * NB1 + blk];
    __syncthreads();
    int base = blk * CHUNK;
    for (int i = 0; i < CHUNK; i += 256) {
        int e = base + i + tid;
        if (e < Ee) {
            int d = dst[e];
            int p = atomicAdd(&cur[d >> 8], 1);
            pairs[p] = ((unsigned int)(d & 255) << 16) | (unsigned int)srcv[e];
        }
    }
}

__global__ void k_sortD(const unsigned int* __restrict__ pairs, const int* __restrict__ Goff,
                        int* __restrict__ offs, int* __restrict__ srcs, float* __restrict__ invc) {
    __shared__ int fcnt[256];
    __shared__ int fbase[256];
    __shared__ int s[256];
    int tid = threadIdx.x, cb = blockIdx.x;
    int cbase = Goff[cb * NB1];
    int cend = (cb + 1 < NCB) ? Goff[(cb + 1) * NB1] : Ee;
    fcnt[tid] = 0;
    __syncthreads();
    for (int e = cbase + tid; e < cend; e += 256)
        atomicAdd(&fcnt[pairs[e] >> 16], 1);
    __syncthreads();
    int v = fcnt[tid];
    s[tid] = v;
    __syncthreads();
    for (int off = 1; off < 256; off <<= 1) {
        int t = (tid >= off) ? s[tid - off] : 0;
        __syncthreads();
        s[tid] += t;
        __syncthreads();
    }
    fbase[tid] = cbase + s[tid] - v;
    int node = cb * 256 + tid;
    if (node < Nn) {
        offs[node] = fbase[tid];
        invc[node] = 1.0f / (float)(v > 1 ? v : 1);
    }
    __syncthreads();
    fcnt[tid] = fbase[tid];
    __syncthreads();
    for (int e = cbase + tid; e < cend; e += 256) {
        unsigned int pv = pairs[e];
        int p = atomicAdd(&fcnt[pv >> 16], 1);
        srcs[p] = (int)(pv & 0xFFFFu);
    }
}

__global__ void k_bsearch(const int* __restrict__ batch, int* __restrict__ boff,
                          int* __restrict__ offs) {
    int b = threadIdx.x;
    if (b <= Bb) {
        int lo = 0, hi = Nn;
        while (lo < hi) {
            int mid = (lo + hi) >> 1;
            if (batch[mid] < b) lo = mid + 1; else hi = mid;
        }
        boff[b] = lo;
    }
    if (b == 0) offs[Nn] = Ee;
}

// ---------------- weight prep: fragment-ordered bf16 ----------------
// chunk G = (p*NT + T)*64 + lane (p = half-stage 0..15) holds 8 bf16:
//   W[k = (p>>1)*... ] exactly as consumed by k_gemm_mfma step p.

template <int NOUT>
__global__ void k_prepW(const float* __restrict__ Wl, const float* __restrict__ Wr,
                        uint4* __restrict__ outw) {
    constexpr int NT = NOUT / 16;
    int G = blockIdx.x * 256 + threadIdx.x;
    int per = 2 * NT * 64;
    int S = G / per, rem = G % per;
    int lane = rem & 63, sT = rem >> 6;
    int s = sT / NT, T = sT % NT;
    int q = lane >> 4, m = lane & 15;
    int k0 = S * 64 + s * 32 + q * 8;
    int nc = T * 16 + m;
    union { uint4 u; unsigned short h[8]; } pk;
#pragma unroll
    for (int j = 0; j < 8; j++) {
        int kk = k0 + j;
        float wv = (kk < 256) ? Wl[kk * NOUT + nc] : Wr[(kk - 256) * NOUT + nc];
        pk.h[j] = f2bf(wv);
    }
    outw[G] = pk.u;
}

// ---------------- aggregation ----------------

__global__ void k_agg15(const float* __restrict__ x, const int* __restrict__ offs,
                        const int* __restrict__ srcs, const float* __restrict__ invc,
                        float* __restrict__ mean15) {
    int node = blockIdx.x * 16 + (threadIdx.x >> 4);
    int f = threadIdx.x & 15;
    int s0 = offs[node], s1 = offs[node + 1];
    float acc = 0.0f;
    for (int i = s0; i < s1; i++) {
        int s = srcs[i];
        if (f < 15) acc += x[s * INF + f];
    }
    if (f < 15) mean15[node * INF + f] = acc * invc[node];
}

__global__ void k_agg256_bf(const uint4* __restrict__ h4, const int* __restrict__ offs,
                            const int* __restrict__ srcs, const float* __restrict__ invc,
                            uint4* __restrict__ mean4) {
    int node = blockIdx.x * 4 + (threadIdx.x >> 6);
    int lane = threadIdx.x & 63;
    int sub = lane >> 5, q = lane & 31;
    int s0 = offs[node], s1 = offs[node + 1];
    int deg = s1 - s0;
    int dcap = deg < 64 ? deg : 64;
    int myidx = (lane < deg) ? srcs[s0 + lane] : 0;
    float a[8] = {};
    int i = 0;
    for (; i + 4 <= dcap; i += 4) {
        int sA = __shfl(myidx, i + sub);
        int sB = __shfl(myidx, i + 2 + sub);
        uint4 vA = h4[(size_t)sA * 32 + q];
        uint4 vB = h4[(size_t)sB * 32 + q];
        a[0] += bflo(vA.x); a[1] += bfhi(vA.x);
        a[2] += bflo(vA.y); a[3] += bfhi(vA.y);
        a[4] += bflo(vA.z); a[5] += bfhi(vA.z);
        a[6] += bflo(vA.w); a[7] += bfhi(vA.w);
        a[0] += bflo(vB.x); a[1] += bfhi(vB.x);
        a[2] += bflo(vB.y); a[3] += bfhi(vB.y);
        a[4] += bflo(vB.z); a[5] += bfhi(vB.z);
        a[6] += bflo(vB.w); a[7] += bfhi(vB.w);
    }
    if (i + 2 <= dcap) {
        int sA = __shfl(myidx, i + sub);
        uint4 vA = h4[(size_t)sA * 32 + q];
        a[0] += bflo(vA.x); a[1] += bfhi(vA.x);
        a[2] += bflo(vA.y); a[3] += bfhi(vA.y);
        a[4] += bflo(vA.z); a[5] += bfhi(vA.z);
        a[6] += bflo(vA.w); a[7] += bfhi(vA.w);
        i += 2;
    }
    if (i < dcap && sub == 0) {
        int sA = __shfl(myidx, i);
        uint4 vA = h4[(size_t)sA * 32 + q];
        a[0] += bflo(vA.x); a[1] += bfhi(vA.x);
        a[2] += bflo(vA.y); a[3] += bfhi(vA.y);
        a[4] += bflo(vA.z); a[5] += bfhi(vA.z);
        a[6] += bflo(vA.w); a[7] += bfhi(vA.w);
    }
    for (int j = 64; j + 1 < deg; j += 2) {
        int s = srcs[s0 + j + sub];
        uint4 v = h4[(size_t)s * 32 + q];
        a[0] += bflo(v.x); a[1] += bfhi(v.x);
        a[2] += bflo(v.y); a[3] += bfhi(v.y);
        a[4] += bflo(v.z); a[5] += bfhi(v.z);
        a[6] += bflo(v.w); a[7] += bfhi(v.w);
    }
    if (deg > 64 && ((deg - 64) & 1) && sub == 0) {
        int s = srcs[s1 - 1];
        uint4 v = h4[(size_t)s * 32 + q];
        a[0] += bflo(v.x); a[1] += bfhi(v.x);
        a[2] += bflo(v.y); a[3] += bfhi(v.y);
        a[4] += bflo(v.z); a[5] += bfhi(v.z);
        a[6] += bflo(v.w); a[7] += bfhi(v.w);
    }
#pragma unroll
    for (int j = 0; j < 8; j++) a[j] += __shfl_xor(a[j], 32);
    if (sub == 0) {
        float ic = invc[node];
        uint4 o;
        o.x = (unsigned int)f2bf(a[0] * ic) | ((unsigned int)f2bf(a[1] * ic) << 16);
        o.y = (unsigned int)f2bf(a[2] * ic) | ((unsigned int)f2bf(a[3] * ic) << 16);
        o.z = (unsigned int)f2bf(a[4] * ic) | ((unsigned int)f2bf(a[5] * ic) << 16);
        o.w = (unsigned int)f2bf(a[6] * ic) | ((unsigned int)f2bf(a[7] * ic) << 16);
        mean4[(size_t)node * 32 + q] = o;
    }
}

// ---------------- layer 1 GEMM (K=15) + LN + GELU ----------------

__global__ void k_gemm1(const float* __restrict__ mean15, const float* __restrict__ x,
                        const float* __restrict__ Wl, const float* __restrict__ Wr,
                        const float* __restrict__ bias, const float* __restrict__ g,
                        const float* __restrict__ bt, unsigned short* __restrict__ out) {
    int n = blockIdx.x;
    int j = threadIdx.x;
    __shared__ float sm[INF], sx[INF];
    __shared__ float red[8];
    if (j < 15) sm[j] = mean15[n * INF + j];
    else if (j >= 16 && j < 31) sx[j - 16] = x[n * INF + (j - 16)];
    __syncthreads();
    float acc = bias[j];
#pragma unroll
    for (int k = 0; k < INF; k++)
        acc += sm[k] * Wl[k * HID + j] + sx[k] * Wr[k * HID + j];
    float s1 = acc, s2 = acc * acc;
#pragma unroll
    for (int o = 32; o; o >>= 1) { s1 += __shfl_xor(s1, o); s2 += __shfl_xor(s2, o); }
    int wid = j >> 6, lane = j & 63;
    if (lane == 0) { red[wid] = s1; red[4 + wid] = s2; }
    __syncthreads();
    float ts1 = red[0] + red[1] + red[2] + red[3];
    float ts2 = red[4] + red[5] + red[6] + red[7];
    float mu = ts1 * (1.0f / HID);
    float var = ts2 * (1.0f / HID) - mu * mu;
    float rs = 1.0f / sqrtf(var + 1e-5f);
    float y = (acc - mu) * rs * g[j] + bt[j];
    out[(size_t)n * HID + j] = f2bf(gelu_f(y));
}

// ---------------- MFMA GEMM, barrier-free K-loop, B direct from L2 ----------------
// 16 half-stages (p = 0..15): p<8 -> A = mean, else h; K-offset
// kk = ((p>>1)&3)*64 + (p&1)*32 + q*8. Software-pipelined: prefetch p+1 while
// computing p. No __syncthreads until the LN epilogue.

template <int NOUT, bool F32OUT>
__global__ __launch_bounds__(256) void k_gemm_mfma(
    const unsigned short* __restrict__ Am,
    const unsigned short* __restrict__ Ah,
    const uint4* __restrict__ Wfrag,
    const float* __restrict__ bias, const float* __restrict__ g,
    const float* __restrict__ bt, void* __restrict__ outp, int n) {
    constexpr int NT = NOUT / 16;
    constexpr int CT = NT / 4;
    __shared__ float lnbuf[2][4][64];
    int tid = threadIdx.x;
    int w = tid >> 6, lane = tid & 63;
    int q = lane >> 4, m = lane & 15;
    int rowbase = blockIdx.x * 64;

    f32x4 acc[4][CT];
#pragma unroll
    for (int i = 0; i < 4; i++)
#pragma unroll
        for (int t = 0; t < CT; t++) acc[i][t] = (f32x4)0.f;

    union U { uint4 u; bf16x8 b; };
    U a[2][4], b[2][CT];

    auto loadA = [&](int p, U* ar) {
        const unsigned short* A = (p < 8) ? Am : Ah;
        int kk = ((p >> 1) & 3) * 64 + (p & 1) * 32 + q * 8;
#pragma unroll
        for (int i = 0; i < 4; i++)
            ar[i].u = *(const uint4*)(A + (size_t)(rowbase + i * 16 + m) * 256 + kk);
    };
    auto loadB = [&](int p, U* br) {
#pragma unroll
        for (int t = 0; t < CT; t++)
            br[t].u = Wfrag[(size_t)(p * NT + w * CT + t) * 64 + lane];
    };

    loadA(0, a[0]);
    loadB(0, b[0]);
#pragma unroll
    for (int p = 0; p < 16; p++) {
        int cur = p & 1, nxt = cur ^ 1;
        if (p < 15) {
            loadA(p + 1, a[nxt]);
            loadB(p + 1, b[nxt]);
        }
#pragma unroll
        for (int i = 0; i < 4; i++)
#pragma unroll
            for (int t = 0; t < CT; t++)
                acc[i][t] = __builtin_amdgcn_mfma_f32_16x16x32_bf16(
                    a[cur][i].b, b[cur][t].b, acc[i][t], 0, 0, 0);
    }

    int col0 = w * CT * 16;
    float bv[CT], gv[CT], btv[CT];
#pragma unroll
    for (int t = 0; t < CT; t++) {
        int c = col0 + t * 16 + m;
        bv[t] = bias[c]; gv[t] = g[c]; btv[t] = bt[c];
    }
#pragma unroll
    for (int i = 0; i < 4; i++) {
#pragma unroll
        for (int r = 0; r < 4; r++) {
            float s1 = 0.f, s2 = 0.f;
#pragma unroll
            for (int t = 0; t < CT; t++) {
                float v = acc[i][t][r] + bv[t];
                acc[i][t][r] = v;
                s1 += v; s2 += v * v;
            }
#pragma unroll
            for (int o = 1; o < 16; o <<= 1) {
                s1 += __shfl_xor(s1, o);
                s2 += __shfl_xor(s2, o);
            }
            if (m == 0) {
                int row = i * 16 + q * 4 + r;
                lnbuf[0][w][row] = s1;
                lnbuf[1][w][row] = s2;
            }
        }
    }
    __syncthreads();
#pragma unroll
    for (int i = 0; i < 4; i++) {
#pragma unroll
        for (int r = 0; r < 4; r++) {
            int rit = i * 16 + q * 4 + r;
            float ts1 = lnbuf[0][0][rit] + lnbuf[0][1][rit] + lnbuf[0][2][rit] + lnbuf[0][3][rit];
            float ts2 = lnbuf[1][0][rit] + lnbuf[1][1][rit] + lnbuf[1][2][rit] + lnbuf[1][3][rit];
            float mu  = ts1 * (1.0f / NOUT);
            float var = ts2 * (1.0f / NOUT) - mu * mu;
            float rs  = 1.0f / sqrtf(var + 1e-5f);
            int row = rowbase + rit;
            if (row < n) {
#pragma unroll
                for (int t = 0; t < CT; t++) {
                    int c = col0 + t * 16 + m;
                    float y = (acc[i][t][r] - mu) * rs * gv[t] + btv[t];
                    float res = gelu_f(y);
                    if (F32OUT) ((float*)outp)[(size_t)row * NOUT + c] = res;
                    else ((unsigned short*)outp)[(size_t)row * NOUT + c] = f2bf(res);
                }
            }
        }
    }
}

// ---------------- pool ----------------

__global__ __launch_bounds__(1024) void k_pool(const float* __restrict__ h,
                                               const int* __restrict__ boff,
                                               float* __restrict__ out) {
    __shared__ float red[8][128];
    int b = blockIdx.x, tid = threadIdx.x;
    int j = tid & 127, grp = tid >> 7;
    int s0 = boff[b], s1 = boff[b + 1];
    float a0 = 0.f, a1 = 0.f, a2 = 0.f, a3 = 0.f;
    int i = s0 + grp;
    for (; i + 24 < s1; i += 32) {
        a0 += h[(size_t)i * OUTF + j];
        a1 += h[(size_t)(i + 8) * OUTF + j];
        a2 += h[(size_t)(i + 16) * OUTF + j];
        a3 += h[(size_t)(i + 24) * OUTF + j];
    }
    for (; i < s1; i += 8) a0 += h[(size_t)i * OUTF + j];
    red[grp][j] = (a0 + a1) + (a2 + a3);
    __syncthreads();
    if (tid < 128) {
        float s = ((red[0][tid] + red[1][tid]) + (red[2][tid] + red[3][tid]))
                + ((red[4][tid] + red[5][tid]) + (red[6][tid] + red[7][tid]));
        int c = s1 - s0;
        out[b * OUTF + tid] = s / fmaxf((float)c, 1.0f);
    }
}

// ---------------- launch ----------------

extern "C" void kernel_launch(void* const* d_in, const int* in_sizes, int n_in,
                              void* d_out, int out_size, void* d_ws, size_t ws_size,
                              hipStream_t stream) {
    const float* x     = (const float*)d_in[0];
    const int*   ei    = (const int*)d_in[1];
    const int*   src   = ei;
    const int*   dst   = ei + Ee;
    const int*   batch = (const int*)d_in[2];
    const float* Wl1 = (const float*)d_in[3];
    const float* Wr1 = (const float*)d_in[4];
    const float* b1  = (const float*)d_in[5];
    const float* g1  = (const float*)d_in[6];
    const float* bt1 = (const float*)d_in[7];
    const float* Wl2 = (const float*)d_in[8];
    const float* Wr2 = (const float*)d_in[9];
    const float* b2  = (const float*)d_in[10];
    const float* g2  = (const float*)d_in[11];
    const float* bt2 = (const float*)d_in[12];
    const float* Wl3 = (const float*)d_in[13];
    const float* Wr3 = (const float*)d_in[14];
    const float* b3  = (const float*)d_in[15];
    const float* g3  = (const float*)d_in[16];
    const float* bt3 = (const float*)d_in[17];
    const float* Wl4 = (const float*)d_in[18];
    const float* Wr4 = (const float*)d_in[19];
    const float* b4  = (const float*)d_in[20];
    const float* g4  = (const float*)d_in[21];
    const float* bt4 = (const float*)d_in[22];
    float* out = (float*)d_out;

    char* ws = (char*)d_ws;
    size_t off = 0;
    auto alloc = [&](size_t bytes) -> char* {
        char* p = ws + off;
        off = (off + bytes + 255) & ~(size_t)255;
        return p;
    };
    int*   offs    = (int*)alloc((size_t)(Nn + 1) * 4);
    int*   srcs    = (int*)alloc((size_t)Ee * 4);
    float* invc    = (float*)alloc((size_t)Nn * 4);
    int*   boff    = (int*)alloc((size_t)(Bb + 1) * 4);
    unsigned int* pairs = (unsigned int*)alloc((size_t)Ee * 4);
    int*   Gcnt    = (int*)alloc((size_t)SCANN * 4);
    int*   Goff    = (int*)alloc((size_t)SCANN * 4);
    int*   partial = (int*)alloc(256 * 4);
    float* mean15  = (float*)alloc((size_t)Nn * INF * 4);
    unsigned short* meanb = (unsigned short*)alloc((size_t)Nn * HID * 2);
    unsigned short* hA    = (unsigned short*)alloc((size_t)Nn * HID * 2);
    unsigned short* hB    = (unsigned short*)alloc((size_t)Nn * HID * 2);
    float* hOut    = (float*)alloc((size_t)Nn * OUTF * 4);
    uint4* W2f     = (uint4*)alloc((size_t)512 * HID * 2);
    uint4* W3f     = (uint4*)alloc((size_t)512 * HID * 2);
    uint4* W4f     = (uint4*)alloc((size_t)512 * OUTF * 2);

    int nbScan = (SCANN + 255) / 256;
    k_sortA<<<NB1, 256, 0, stream>>>(dst, Gcnt);
    k_gscan_partial<<<nbScan, 256, 0, stream>>>(Gcnt, partial, SCANN);
    k_gscan_mid<<<1, 256, 0, stream>>>(partial, nbScan);
    k_gscan_final<<<nbScan, 256, 0, stream>>>(Gcnt, partial, Goff, SCANN);
    k_sortC<<<NB1, 256, 0, stream>>>(dst, src, Goff, pairs);
    k_sortD<<<NCB, 256, 0, stream>>>(pairs, Goff, offs, srcs, invc);
    k_bsearch<<<1, 256, 0, stream>>>(batch, boff, offs);

    k_prepW<256><<<64, 256, 0, stream>>>(Wl2, Wr2, W2f);
    k_prepW<256><<<64, 256, 0, stream>>>(Wl3, Wr3, W3f);
    k_prepW<128><<<32, 256, 0, stream>>>(Wl4, Wr4, W4f);

    int gb = (Nn + 63) / 64;
    // layer 1
    k_agg15<<<Nn / 16, 256, 0, stream>>>(x, offs, srcs, invc, mean15);
    k_gemm1<<<Nn, 256, 0, stream>>>(mean15, x, Wl1, Wr1, b1, g1, bt1, hA);
    // layer 2
    k_agg256_bf<<<Nn / 4, 256, 0, stream>>>((const uint4*)hA, offs, srcs, invc, (uint4*)meanb);
    k_gemm_mfma<256, false><<<gb, 256, 0, stream>>>(meanb, hA, W2f, b2, g2, bt2, hB, Nn);
    // layer 3
    k_agg256_bf<<<Nn / 4, 256, 0, stream>>>((const uint4*)hB, offs, srcs, invc, (uint4*)meanb);
    k_gemm_mfma<256, false><<<gb, 256, 0, stream>>>(meanb, hB, W3f, b3, g3, bt3, hA, Nn);
    // layer 4
    k_agg256_bf<<<Nn / 4, 256, 0, stream>>>((const uint4*)hA, offs, srcs, invc, (uint4*)meanb);
    k_gemm_mfma<128, true><<<gb, 256, 0, stream>>>(meanb, hA, W4f, b4, g4, bt4, hOut, Nn);
    // pool
    k_pool<<<Bb, 1024, 0, stream>>>(hOut, boff, out);
}

// Round 6
// 566.588 us; speedup vs baseline: 2.5625x; 1.0417x over previous
//
#include <hip/hip_runtime.h>
#include <math.h>

constexpr int Nn   = 50000;
constexpr int Ee   = 800000;
constexpr int Bb   = 128;
constexpr int INF  = 15;
constexpr int HID  = 256;
constexpr int OUTF = 128;

constexpr int NCB   = (Nn + 255) / 256;   // 196 coarse buckets (dst>>8)
constexpr int CHUNK = 4096;
constexpr int NB1   = (Ee + CHUNK - 1) / CHUNK;  // 196 sort blocks
constexpr int SCANN = NCB * NB1;          // 38416

typedef __attribute__((ext_vector_type(8))) __bf16 bf16x8;
typedef __attribute__((ext_vector_type(4))) float  f32x4;

__device__ __forceinline__ float gelu_f(float v) {
    return 0.5f * v * (1.0f + erff(v * 0.7071067811865475f));
}

__device__ __forceinline__ unsigned short f2bf(float f) {
    union { float f; unsigned int u; } v; v.f = f;
    unsigned int r = v.u + 0x7fffu + ((v.u >> 16) & 1u);   // RNE
    return (unsigned short)(r >> 16);
}

__device__ __forceinline__ float bflo(unsigned int p) { return __uint_as_float(p << 16); }
__device__ __forceinline__ float bfhi(unsigned int p) { return __uint_as_float(p & 0xffff0000u); }

// ---------------- CSR build: two-level counting sort (LDS atomics only) ----------------

__global__ void k_sortA(const int* __restrict__ dst, int* __restrict__ Gcnt) {
    __shared__ int cnt[NCB];
    int tid = threadIdx.x, blk = blockIdx.x;
    for (int i = tid; i < NCB; i += 256) cnt[i] = 0;
    __syncthreads();
    int base = blk * CHUNK;
    for (int i = 0; i < CHUNK; i += 256) {
        int e = base + i + tid;
        if (e < Ee) atomicAdd(&cnt[dst[e] >> 8], 1);
    }
    __syncthreads();
    for (int i = tid; i < NCB; i += 256) Gcnt[i * NB1 + blk] = cnt[i];
}

__global__ void k_gscan_partial(const int* __restrict__ in, int* __restrict__ partial, int n) {
    __shared__ int s[256];
    int tid = threadIdx.x, i = blockIdx.x * 256 + tid;
    s[tid] = (i < n) ? in[i] : 0;
    __syncthreads();
    for (int off = 128; off; off >>= 1) {
        if (tid < off) s[tid] += s[tid + off];
        __syncthreads();
    }
    if (tid == 0) partial[blockIdx.x] = s[0];
}

__global__ void k_gscan_mid(int* __restrict__ partial, int nb) {
    __shared__ int s[256];
    int tid = threadIdx.x;
    int v = (tid < nb) ? partial[tid] : 0;
    s[tid] = v;
    __syncthreads();
    for (int off = 1; off < 256; off <<= 1) {
        int t = (tid >= off) ? s[tid - off] : 0;
        __syncthreads();
        s[tid] += t;
        __syncthreads();
    }
    if (tid < nb) partial[tid] = s[tid] - v;
}

__global__ void k_gscan_final(const int* __restrict__ in, const int* __restrict__ partial,
                              int* __restrict__ out, int n) {
    __shared__ int s[256];
    int tid = threadIdx.x, i = blockIdx.x * 256 + tid;
    int v = (i < n) ? in[i] : 0;
    s[tid] = v;
    __syncthreads();
    for (int off = 1; off < 256; off <<= 1) {
        int t = (tid >= off) ? s[tid - off] : 0;
        __syncthreads();
        s[tid] += t;
        __syncthreads();
    }
    if (i < n) out[i] = s[tid] - v + partial[blockIdx.x];
}

__global__ void k_sortC(const int* __restrict__ dst, const int* __restrict__ srcv,
                        const int* __restrict__ Goff, unsigned int* __restrict__ pairs) {
    __shared__ int cur[NCB];
    int tid = threadIdx.x, blk = blockIdx.x;
    for (int i = tid; i < NCB; i += 256) cur[i] = Goff[i * NB1 + blk];
    __syncthreads();
    int base = blk * CHUNK;
    for (int i = 0; i < CHUNK; i += 256) {
        int e = base + i + tid;
        if (e < Ee) {
            int d = dst[e];
            int p = atomicAdd(&cur[d >> 8], 1);
            pairs[p] = ((unsigned int)(d & 255) << 16) | (unsigned int)srcv[e];
        }
    }
}

__global__ void k_sortD(const unsigned int* __restrict__ pairs, const int* __restrict__ Goff,
                        int* __restrict__ offs, int* __restrict__ srcs, float* __restrict__ invc) {
    __shared__ int fcnt[256];
    __shared__ int fbase[256];
    __shared__ int s[256];
    int tid = threadIdx.x, cb = blockIdx.x;
    int cbase = Goff[cb * NB1];
    int cend = (cb + 1 < NCB) ? Goff[(cb + 1) * NB1] : Ee;
    fcnt[tid] = 0;
    __syncthreads();
    for (int e = cbase + tid; e < cend; e += 256)
        atomicAdd(&fcnt[pairs[e] >> 16], 1);
    __syncthreads();
    int v = fcnt[tid];
    s[tid] = v;
    __syncthreads();
    for (int off = 1; off < 256; off <<= 1) {
        int t = (tid >= off) ? s[tid - off] : 0;
        __syncthreads();
        s[tid] += t;
        __syncthreads();
    }
    fbase[tid] = cbase + s[tid] - v;
    int node = cb * 256 + tid;
    if (node < Nn) {
        offs[node] = fbase[tid];
        invc[node] = 1.0f / (float)(v > 1 ? v : 1);
    }
    __syncthreads();
    fcnt[tid] = fbase[tid];
    __syncthreads();
    for (int e = cbase + tid; e < cend; e += 256) {
        unsigned int pv = pairs[e];
        int p = atomicAdd(&fcnt[pv >> 16], 1);
        srcs[p] = (int)(pv & 0xFFFFu);
    }
}

__global__ void k_bsearch(const int* __restrict__ batch, int* __restrict__ boff,
                          int* __restrict__ offs) {
    int b = threadIdx.x;
    if (b <= Bb) {
        int lo = 0, hi = Nn;
        while (lo < hi) {
            int mid = (lo + hi) >> 1;
            if (batch[mid] < b) lo = mid + 1; else hi = mid;
        }
        boff[b] = lo;
    }
    if (b == 0) offs[Nn] = Ee;
}

// ---------------- weight prep (layers 2-4): fragment-ordered bf16 ----------------

template <int NOUT>
__global__ void k_prepW(const float* __restrict__ Wl, const float* __restrict__ Wr,
                        uint4* __restrict__ outw) {
    constexpr int NT = NOUT / 16;
    int G = blockIdx.x * 256 + threadIdx.x;
    int per = 2 * NT * 64;
    int S = G / per, rem = G % per;
    int lane = rem & 63, sT = rem >> 6;
    int s = sT / NT, T = sT % NT;
    int q = lane >> 4, m = lane & 15;
    int k0 = S * 64 + s * 32 + q * 8;
    int nc = T * 16 + m;
    union { uint4 u; unsigned short h[8]; } pk;
#pragma unroll
    for (int j = 0; j < 8; j++) {
        int kk = k0 + j;
        float wv = (kk < 256) ? Wl[kk * NOUT + nc] : Wr[(kk - 256) * NOUT + nc];
        pk.h[j] = f2bf(wv);
    }
    outw[G] = pk.u;
}

// layer 1: [Wl1(15) | 0 | Wr1(15) | 0] -> K=32 fragment order, NT=16 tiles
__global__ void k_prepW1(const float* __restrict__ Wl, const float* __restrict__ Wr,
                         uint4* __restrict__ outw) {
    int G = blockIdx.x * 256 + threadIdx.x;   // 0..1023
    int T = G >> 6, lane = G & 63;
    int q = lane >> 4, m = lane & 15;
    int nc = T * 16 + m;
    union { uint4 u; unsigned short h[8]; } pk;
#pragma unroll
    for (int j = 0; j < 8; j++) {
        int k = q * 8 + j;
        float wv;
        if (k < 15)       wv = Wl[k * HID + nc];
        else if (k == 15) wv = 0.0f;
        else if (k < 31)  wv = Wr[(k - 16) * HID + nc];
        else              wv = 0.0f;
        pk.h[j] = f2bf(wv);
    }
    outw[G] = pk.u;
}

// ---------------- layer-1 A build: A1[node][32] = [mean15|0|x15|0] bf16 ----------------
// 16 lanes per node (same pattern as old k_agg15), fuses aggregation + x cast.

__global__ void k_prep1(const float* __restrict__ x, const int* __restrict__ offs,
                        const int* __restrict__ srcs, const float* __restrict__ invc,
                        unsigned short* __restrict__ A1) {
    int node = blockIdx.x * 16 + (threadIdx.x >> 4);
    int f = threadIdx.x & 15;
    int s0 = offs[node], s1 = offs[node + 1];
    float acc = 0.0f;
    for (int i = s0; i < s1; i++) {
        int s = srcs[i];
        if (f < 15) acc += x[s * INF + f];
    }
    unsigned short mv = (f < 15) ? f2bf(acc * invc[node]) : (unsigned short)0;
    unsigned short xv = (f < 15) ? f2bf(x[(size_t)node * INF + f]) : (unsigned short)0;
    A1[(size_t)node * 32 + f] = mv;
    A1[(size_t)node * 32 + 16 + f] = xv;
}

// ---------------- aggregation (256-d bf16) ----------------

__global__ void k_agg256_bf(const uint4* __restrict__ h4, const int* __restrict__ offs,
                            const int* __restrict__ srcs, const float* __restrict__ invc,
                            uint4* __restrict__ mean4) {
    int node = blockIdx.x * 4 + (threadIdx.x >> 6);
    int lane = threadIdx.x & 63;
    int sub = lane >> 5, q = lane & 31;
    int s0 = offs[node], s1 = offs[node + 1];
    int deg = s1 - s0;
    int dcap = deg < 64 ? deg : 64;
    int myidx = (lane < deg) ? srcs[s0 + lane] : 0;
    float a[8] = {};
    int i = 0;
    for (; i + 4 <= dcap; i += 4) {
        int sA = __shfl(myidx, i + sub);
        int sB = __shfl(myidx, i + 2 + sub);
        uint4 vA = h4[(size_t)sA * 32 + q];
        uint4 vB = h4[(size_t)sB * 32 + q];
        a[0] += bflo(vA.x); a[1] += bfhi(vA.x);
        a[2] += bflo(vA.y); a[3] += bfhi(vA.y);
        a[4] += bflo(vA.z); a[5] += bfhi(vA.z);
        a[6] += bflo(vA.w); a[7] += bfhi(vA.w);
        a[0] += bflo(vB.x); a[1] += bfhi(vB.x);
        a[2] += bflo(vB.y); a[3] += bfhi(vB.y);
        a[4] += bflo(vB.z); a[5] += bfhi(vB.z);
        a[6] += bflo(vB.w); a[7] += bfhi(vB.w);
    }
    if (i + 2 <= dcap) {
        int sA = __shfl(myidx, i + sub);
        uint4 vA = h4[(size_t)sA * 32 + q];
        a[0] += bflo(vA.x); a[1] += bfhi(vA.x);
        a[2] += bflo(vA.y); a[3] += bfhi(vA.y);
        a[4] += bflo(vA.z); a[5] += bfhi(vA.z);
        a[6] += bflo(vA.w); a[7] += bfhi(vA.w);
        i += 2;
    }
    if (i < dcap && sub == 0) {
        int sA = __shfl(myidx, i);
        uint4 vA = h4[(size_t)sA * 32 + q];
        a[0] += bflo(vA.x); a[1] += bfhi(vA.x);
        a[2] += bflo(vA.y); a[3] += bfhi(vA.y);
        a[4] += bflo(vA.z); a[5] += bfhi(vA.z);
        a[6] += bflo(vA.w); a[7] += bfhi(vA.w);
    }
    for (int j = 64; j + 1 < deg; j += 2) {
        int s = srcs[s0 + j + sub];
        uint4 v = h4[(size_t)s * 32 + q];
        a[0] += bflo(v.x); a[1] += bfhi(v.x);
        a[2] += bflo(v.y); a[3] += bfhi(v.y);
        a[4] += bflo(v.z); a[5] += bfhi(v.z);
        a[6] += bflo(v.w); a[7] += bfhi(v.w);
    }
    if (deg > 64 && ((deg - 64) & 1) && sub == 0) {
        int s = srcs[s1 - 1];
        uint4 v = h4[(size_t)s * 32 + q];
        a[0] += bflo(v.x); a[1] += bfhi(v.x);
        a[2] += bflo(v.y); a[3] += bfhi(v.y);
        a[4] += bflo(v.z); a[5] += bfhi(v.z);
        a[6] += bflo(v.w); a[7] += bfhi(v.w);
    }
#pragma unroll
    for (int j = 0; j < 8; j++) a[j] += __shfl_xor(a[j], 32);
    if (sub == 0) {
        float ic = invc[node];
        uint4 o;
        o.x = (unsigned int)f2bf(a[0] * ic) | ((unsigned int)f2bf(a[1] * ic) << 16);
        o.y = (unsigned int)f2bf(a[2] * ic) | ((unsigned int)f2bf(a[3] * ic) << 16);
        o.z = (unsigned int)f2bf(a[4] * ic) | ((unsigned int)f2bf(a[5] * ic) << 16);
        o.w = (unsigned int)f2bf(a[6] * ic) | ((unsigned int)f2bf(a[7] * ic) << 16);
        mean4[(size_t)node * 32 + q] = o;
    }
}

// ---------------- MFMA GEMM, barrier-free K-loop, B direct from L2 ----------------

template <int NOUT, bool F32OUT>
__global__ __launch_bounds__(256) void k_gemm_mfma(
    const unsigned short* __restrict__ Am,
    const unsigned short* __restrict__ Ah,
    const uint4* __restrict__ Wfrag,
    const float* __restrict__ bias, const float* __restrict__ g,
    const float* __restrict__ bt, void* __restrict__ outp, int n) {
    constexpr int NT = NOUT / 16;
    constexpr int CT = NT / 4;
    __shared__ float lnbuf[2][4][64];
    int tid = threadIdx.x;
    int w = tid >> 6, lane = tid & 63;
    int q = lane >> 4, m = lane & 15;
    int rowbase = blockIdx.x * 64;

    f32x4 acc[4][CT];
#pragma unroll
    for (int i = 0; i < 4; i++)
#pragma unroll
        for (int t = 0; t < CT; t++) acc[i][t] = (f32x4)0.f;

    union U { uint4 u; bf16x8 b; };
    U a[2][4], b[2][CT];

    auto loadA = [&](int p, U* ar) {
        const unsigned short* A = (p < 8) ? Am : Ah;
        int kk = ((p >> 1) & 3) * 64 + (p & 1) * 32 + q * 8;
#pragma unroll
        for (int i = 0; i < 4; i++)
            ar[i].u = *(const uint4*)(A + (size_t)(rowbase + i * 16 + m) * 256 + kk);
    };
    auto loadB = [&](int p, U* br) {
#pragma unroll
        for (int t = 0; t < CT; t++)
            br[t].u = Wfrag[(size_t)(p * NT + w * CT + t) * 64 + lane];
    };

    loadA(0, a[0]);
    loadB(0, b[0]);
#pragma unroll
    for (int p = 0; p < 16; p++) {
        int cur = p & 1, nxt = cur ^ 1;
        if (p < 15) {
            loadA(p + 1, a[nxt]);
            loadB(p + 1, b[nxt]);
        }
#pragma unroll
        for (int i = 0; i < 4; i++)
#pragma unroll
            for (int t = 0; t < CT; t++)
                acc[i][t] = __builtin_amdgcn_mfma_f32_16x16x32_bf16(
                    a[cur][i].b, b[cur][t].b, acc[i][t], 0, 0, 0);
    }

    int col0 = w * CT * 16;
    float bv[CT], gv[CT], btv[CT];
#pragma unroll
    for (int t = 0; t < CT; t++) {
        int c = col0 + t * 16 + m;
        bv[t] = bias[c]; gv[t] = g[c]; btv[t] = bt[c];
    }
#pragma unroll
    for (int i = 0; i < 4; i++) {
#pragma unroll
        for (int r = 0; r < 4; r++) {
            float s1 = 0.f, s2 = 0.f;
#pragma unroll
            for (int t = 0; t < CT; t++) {
                float v = acc[i][t][r] + bv[t];
                acc[i][t][r] = v;
                s1 += v; s2 += v * v;
            }
#pragma unroll
            for (int o = 1; o < 16; o <<= 1) {
                s1 += __shfl_xor(s1, o);
                s2 += __shfl_xor(s2, o);
            }
            if (m == 0) {
                int row = i * 16 + q * 4 + r;
                lnbuf[0][w][row] = s1;
                lnbuf[1][w][row] = s2;
            }
        }
    }
    __syncthreads();
#pragma unroll
    for (int i = 0; i < 4; i++) {
#pragma unroll
        for (int r = 0; r < 4; r++) {
            int rit = i * 16 + q * 4 + r;
            float ts1 = lnbuf[0][0][rit] + lnbuf[0][1][rit] + lnbuf[0][2][rit] + lnbuf[0][3][rit];
            float ts2 = lnbuf[1][0][rit] + lnbuf[1][1][rit] + lnbuf[1][2][rit] + lnbuf[1][3][rit];
            float mu  = ts1 * (1.0f / NOUT);
            float var = ts2 * (1.0f / NOUT) - mu * mu;
            float rs  = 1.0f / sqrtf(var + 1e-5f);
            int row = rowbase + rit;
            if (row < n) {
#pragma unroll
                for (int t = 0; t < CT; t++) {
                    int c = col0 + t * 16 + m;
                    float y = (acc[i][t][r] - mu) * rs * gv[t] + btv[t];
                    float res = gelu_f(y);
                    if (F32OUT) ((float*)outp)[(size_t)row * NOUT + c] = res;
                    else ((unsigned short*)outp)[(size_t)row * NOUT + c] = f2bf(res);
                }
            }
        }
    }
}

// ---------------- layer-1 MFMA GEMM: single K=32 step on A1, LN+GELU ----------------

__global__ __launch_bounds__(256) void k_gemm_mfma1(
    const unsigned short* __restrict__ A1, const uint4* __restrict__ Wfrag,
    const float* __restrict__ bias, const float* __restrict__ g,
    const float* __restrict__ bt, unsigned short* __restrict__ outp, int n) {
    constexpr int NT = 16, CT = 4;
    __shared__ float lnbuf[2][4][64];
    int tid = threadIdx.x;
    int w = tid >> 6, lane = tid & 63;
    int q = lane >> 4, m = lane & 15;
    int rowbase = blockIdx.x * 64;

    union U { uint4 u; bf16x8 b; };
    U a[4], b[CT];
#pragma unroll
    for (int i = 0; i < 4; i++) {
        int row = rowbase + i * 16 + m;
        a[i].u = (row < n) ? *(const uint4*)(A1 + (size_t)row * 32 + q * 8)
                           : make_uint4(0u, 0u, 0u, 0u);
    }
#pragma unroll
    for (int t = 0; t < CT; t++)
        b[t].u = Wfrag[(size_t)(w * CT + t) * 64 + lane];

    f32x4 acc[4][CT];
#pragma unroll
    for (int i = 0; i < 4; i++)
#pragma unroll
        for (int t = 0; t < CT; t++)
            acc[i][t] = __builtin_amdgcn_mfma_f32_16x16x32_bf16(
                a[i].b, b[t].b, (f32x4)0.f, 0, 0, 0);

    int col0 = w * CT * 16;
    float bv[CT], gv[CT], btv[CT];
#pragma unroll
    for (int t = 0; t < CT; t++) {
        int c = col0 + t * 16 + m;
        bv[t] = bias[c]; gv[t] = g[c]; btv[t] = bt[c];
    }
#pragma unroll
    for (int i = 0; i < 4; i++) {
#pragma unroll
        for (int r = 0; r < 4; r++) {
            float s1 = 0.f, s2 = 0.f;
#pragma unroll
            for (int t = 0; t < CT; t++) {
                float v = acc[i][t][r] + bv[t];
                acc[i][t][r] = v;
                s1 += v; s2 += v * v;
            }
#pragma unroll
            for (int o = 1; o < 16; o <<= 1) {
                s1 += __shfl_xor(s1, o);
                s2 += __shfl_xor(s2, o);
            }
            if (m == 0) {
                int row = i * 16 + q * 4 + r;
                lnbuf[0][w][row] = s1;
                lnbuf[1][w][row] = s2;
            }
        }
    }
    __syncthreads();
#pragma unroll
    for (int i = 0; i < 4; i++) {
#pragma unroll
        for (int r = 0; r < 4; r++) {
            int rit = i * 16 + q * 4 + r;
            float ts1 = lnbuf[0][0][rit] + lnbuf[0][1][rit] + lnbuf[0][2][rit] + lnbuf[0][3][rit];
            float ts2 = lnbuf[1][0][rit] + lnbuf[1][1][rit] + lnbuf[1][2][rit] + lnbuf[1][3][rit];
            float mu  = ts1 * (1.0f / HID);
            float var = ts2 * (1.0f / HID) - mu * mu;
            float rs  = 1.0f / sqrtf(var + 1e-5f);
            int row = rowbase + rit;
            if (row < n) {
#pragma unroll
                for (int t = 0; t < CT; t++) {
                    int c = col0 + t * 16 + m;
                    float y = (acc[i][t][r] - mu) * rs * gv[t] + btv[t];
                    outp[(size_t)row * HID + c] = f2bf(gelu_f(y));
                }
            }
        }
    }
}

// ---------------- pool ----------------

__global__ __launch_bounds__(1024) void k_pool(const float* __restrict__ h,
                                               const int* __restrict__ boff,
                                               float* __restrict__ out) {
    __shared__ float red[8][128];
    int b = blockIdx.x, tid = threadIdx.x;
    int j = tid & 127, grp = tid >> 7;
    int s0 = boff[b], s1 = boff[b + 1];
    float a0 = 0.f, a1 = 0.f, a2 = 0.f, a3 = 0.f;
    int i = s0 + grp;
    for (; i + 24 < s1; i += 32) {
        a0 += h[(size_t)i * OUTF + j];
        a1 += h[(size_t)(i + 8) * OUTF + j];
        a2 += h[(size_t)(i + 16) * OUTF + j];
        a3 += h[(size_t)(i + 24) * OUTF + j];
    }
    for (; i < s1; i += 8) a0 += h[(size_t)i * OUTF + j];
    red[grp][j] = (a0 + a1) + (a2 + a3);
    __syncthreads();
    if (tid < 128) {
        float s = ((red[0][tid] + red[1][tid]) + (red[2][tid] + red[3][tid]))
                + ((red[4][tid] + red[5][tid]) + (red[6][tid] + red[7][tid]));
        int c = s1 - s0;
        out[b * OUTF + tid] = s / fmaxf((float)c, 1.0f);
    }
}

// ---------------- launch ----------------

extern "C" void kernel_launch(void* const* d_in, const int* in_sizes, int n_in,
                              void* d_out, int out_size, void* d_ws, size_t ws_size,
                              hipStream_t stream) {
    const float* x     = (const float*)d_in[0];
    const int*   ei    = (const int*)d_in[1];
    const int*   src   = ei;
    const int*   dst   = ei + Ee;
    const int*   batch = (const int*)d_in[2];
    const float* Wl1 = (const float*)d_in[3];
    const float* Wr1 = (const float*)d_in[4];
    const float* b1  = (const float*)d_in[5];
    const float* g1  = (const float*)d_in[6];
    const float* bt1 = (const float*)d_in[7];
    const float* Wl2 = (const float*)d_in[8];
    const float* Wr2 = (const float*)d_in[9];
    const float* b2  = (const float*)d_in[10];
    const float* g2  = (const float*)d_in[11];
    const float* bt2 = (const float*)d_in[12];
    const float* Wl3 = (const float*)d_in[13];
    const float* Wr3 = (const float*)d_in[14];
    const float* b3  = (const float*)d_in[15];
    const float* g3  = (const float*)d_in[16];
    const float* bt3 = (const float*)d_in[17];
    const float* Wl4 = (const float*)d_in[18];
    const float* Wr4 = (const float*)d_in[19];
    const float* b4  = (const float*)d_in[20];
    const float* g4  = (const float*)d_in[21];
    const float* bt4 = (const float*)d_in[22];
    float* out = (float*)d_out;

    char* ws = (char*)d_ws;
    size_t off = 0;
    auto alloc = [&](size_t bytes) -> char* {
        char* p = ws + off;
        off = (off + bytes + 255) & ~(size_t)255;
        return p;
    };
    int*   offs    = (int*)alloc((size_t)(Nn + 1) * 4);
    int*   srcs    = (int*)alloc((size_t)Ee * 4);
    float* invc    = (float*)alloc((size_t)Nn * 4);
    int*   boff    = (int*)alloc((size_t)(Bb + 1) * 4);
    unsigned int* pairs = (unsigned int*)alloc((size_t)Ee * 4);
    int*   Gcnt    = (int*)alloc((size_t)SCANN * 4);
    int*   Goff    = (int*)alloc((size_t)SCANN * 4);
    int*   partial = (int*)alloc(256 * 4);
    unsigned short* A1    = (unsigned short*)alloc((size_t)Nn * 32 * 2);
    unsigned short* meanb = (unsigned short*)alloc((size_t)Nn * HID * 2);
    unsigned short* hA    = (unsigned short*)alloc((size_t)Nn * HID * 2);
    unsigned short* hB    = (unsigned short*)alloc((size_t)Nn * HID * 2);
    float* hOut    = (float*)alloc((size_t)Nn * OUTF * 4);
    uint4* W1f     = (uint4*)alloc((size_t)32 * HID * 2);
    uint4* W2f     = (uint4*)alloc((size_t)512 * HID * 2);
    uint4* W3f     = (uint4*)alloc((size_t)512 * HID * 2);
    uint4* W4f     = (uint4*)alloc((size_t)512 * OUTF * 2);

    int nbScan = (SCANN + 255) / 256;
    k_sortA<<<NB1, 256, 0, stream>>>(dst, Gcnt);
    k_gscan_partial<<<nbScan, 256, 0, stream>>>(Gcnt, partial, SCANN);
    k_gscan_mid<<<1, 256, 0, stream>>>(partial, nbScan);
    k_gscan_final<<<nbScan, 256, 0, stream>>>(Gcnt, partial, Goff, SCANN);
    k_sortC<<<NB1, 256, 0, stream>>>(dst, src, Goff, pairs);
    k_sortD<<<NCB, 256, 0, stream>>>(pairs, Goff, offs, srcs, invc);
    k_bsearch<<<1, 256, 0, stream>>>(batch, boff, offs);

    k_prepW1<<<4, 256, 0, stream>>>(Wl1, Wr1, W1f);
    k_prepW<256><<<64, 256, 0, stream>>>(Wl2, Wr2, W2f);
    k_prepW<256><<<64, 256, 0, stream>>>(Wl3, Wr3, W3f);
    k_prepW<128><<<32, 256, 0, stream>>>(Wl4, Wr4, W4f);

    int gb = (Nn + 63) / 64;
    // layer 1 (MFMA, K=32)
    k_prep1<<<Nn / 16, 256, 0, stream>>>(x, offs, srcs, invc, A1);
    k_gemm_mfma1<<<gb, 256, 0, stream>>>(A1, W1f, b1, g1, bt1, hA, Nn);
    // layer 2
    k_agg256_bf<<<Nn / 4, 256, 0, stream>>>((const uint4*)hA, offs, srcs, invc, (uint4*)meanb);
    k_gemm_mfma<256, false><<<gb, 256, 0, stream>>>(meanb, hA, W2f, b2, g2, bt2, hB, Nn);
    // layer 3
    k_agg256_bf<<<Nn / 4, 256, 0, stream>>>((const uint4*)hB, offs, srcs, invc, (uint4*)meanb);
    k_gemm_mfma<256, false><<<gb, 256, 0, stream>>>(meanb, hB, W3f, b3, g3, bt3, hA, Nn);
    // layer 4
    k_agg256_bf<<<Nn / 4, 256, 0, stream>>>((const uint4*)hA, offs, srcs, invc, (uint4*)meanb);
    k_gemm_mfma<128, true><<<gb, 256, 0, stream>>>(meanb, hA, W4f, b4, g4, bt4, hOut, Nn);
    // pool
    k_pool<<<Bb, 1024, 0, stream>>>(hOut, boff, out);
}

// Round 7
// 513.514 us; speedup vs baseline: 2.8274x; 1.1034x over previous
//
#include <hip/hip_runtime.h>
#include <math.h>

constexpr int Nn   = 50000;
constexpr int Ee   = 800000;
constexpr int Bb   = 128;
constexpr int INF  = 15;
constexpr int HID  = 256;
constexpr int OUTF = 128;

constexpr int NCB   = (Nn + 255) / 256;   // 196 coarse buckets (dst>>8)
constexpr int CHUNK = 4096;
constexpr int NB1   = (Ee + CHUNK - 1) / CHUNK;  // 196 sort blocks
constexpr int SCANN = NCB * NB1;          // 38416

typedef __attribute__((ext_vector_type(8))) __bf16 bf16x8;
typedef __attribute__((ext_vector_type(4))) float  f32x4;

__device__ __forceinline__ float gelu_f(float v) {
    return 0.5f * v * (1.0f + erff(v * 0.7071067811865475f));
}

__device__ __forceinline__ unsigned short f2bf(float f) {
    union { float f; unsigned int u; } v; v.f = f;
    unsigned int r = v.u + 0x7fffu + ((v.u >> 16) & 1u);   // RNE
    return (unsigned short)(r >> 16);
}

__device__ __forceinline__ float bflo(unsigned int p) { return __uint_as_float(p << 16); }
__device__ __forceinline__ float bfhi(unsigned int p) { return __uint_as_float(p & 0xffff0000u); }

// ---------------- CSR build: two-level counting sort (LDS atomics only) ----------------

__global__ void k_sortA(const int* __restrict__ dst, int* __restrict__ Gcnt) {
    __shared__ int cnt[NCB];
    int tid = threadIdx.x, blk = blockIdx.x;
    for (int i = tid; i < NCB; i += 256) cnt[i] = 0;
    __syncthreads();
    int base = blk * CHUNK;
    for (int i = 0; i < CHUNK; i += 256) {
        int e = base + i + tid;
        if (e < Ee) atomicAdd(&cnt[dst[e] >> 8], 1);
    }
    __syncthreads();
    for (int i = tid; i < NCB; i += 256) Gcnt[i * NB1 + blk] = cnt[i];
}

__global__ void k_gscan_partial(const int* __restrict__ in, int* __restrict__ partial, int n) {
    __shared__ int s[256];
    int tid = threadIdx.x, i = blockIdx.x * 256 + tid;
    s[tid] = (i < n) ? in[i] : 0;
    __syncthreads();
    for (int off = 128; off; off >>= 1) {
        if (tid < off) s[tid] += s[tid + off];
        __syncthreads();
    }
    if (tid == 0) partial[blockIdx.x] = s[0];
}

__global__ void k_gscan_mid(int* __restrict__ partial, int nb) {
    __shared__ int s[256];
    int tid = threadIdx.x;
    int v = (tid < nb) ? partial[tid] : 0;
    s[tid] = v;
    __syncthreads();
    for (int off = 1; off < 256; off <<= 1) {
        int t = (tid >= off) ? s[tid - off] : 0;
        __syncthreads();
        s[tid] += t;
        __syncthreads();
    }
    if (tid < nb) partial[tid] = s[tid] - v;
}

__global__ void k_gscan_final(const int* __restrict__ in, const int* __restrict__ partial,
                              int* __restrict__ out, int n) {
    __shared__ int s[256];
    int tid = threadIdx.x, i = blockIdx.x * 256 + tid;
    int v = (i < n) ? in[i] : 0;
    s[tid] = v;
    __syncthreads();
    for (int off = 1; off < 256; off <<= 1) {
        int t = (tid >= off) ? s[tid - off] : 0;
        __syncthreads();
        s[tid] += t;
        __syncthreads();
    }
    if (i < n) out[i] = s[tid] - v + partial[blockIdx.x];
}

__global__ void k_sortC(const int* __restrict__ dst, const int* __restrict__ srcv,
                        const int* __restrict__ Goff, unsigned int* __restrict__ pairs) {
    __shared__ int cur[NCB];
    int tid = threadIdx.x, blk = blockIdx.x;
    for (int i = tid; i < NCB; i += 256) cur[i] = Goff[i * NB1 + blk];
    __syncthreads();
    int base = blk * CHUNK;
    for (int i = 0; i < CHUNK; i += 256) {
        int e = base + i + tid;
        if (e < Ee) {
            int d = dst[e];
            int p = atomicAdd(&cur[d >> 8], 1);
            pairs[p] = ((unsigned int)(d & 255) << 16) | (unsigned int)srcv[e];
        }
    }
}

__global__ void k_sortD(const unsigned int* __restrict__ pairs, const int* __restrict__ Goff,
                        int* __restrict__ offs, int* __restrict__ srcs, float* __restrict__ invc) {
    __shared__ int fcnt[256];
    __shared__ int fbase[256];
    __shared__ int s[256];
    int tid = threadIdx.x, cb = blockIdx.x;
    int cbase = Goff[cb * NB1];
    int cend = (cb + 1 < NCB) ? Goff[(cb + 1) * NB1] : Ee;
    fcnt[tid] = 0;
    __syncthreads();
    for (int e = cbase + tid; e < cend; e += 256)
        atomicAdd(&fcnt[pairs[e] >> 16], 1);
    __syncthreads();
    int v = fcnt[tid];
    s[tid] = v;
    __syncthreads();
    for (int off = 1; off < 256; off <<= 1) {
        int t = (tid >= off) ? s[tid - off] : 0;
        __syncthreads();
        s[tid] += t;
        __syncthreads();
    }
    fbase[tid] = cbase + s[tid] - v;
    int node = cb * 256 + tid;
    if (node < Nn) {
        offs[node] = fbase[tid];
        invc[node] = 1.0f / (float)(v > 1 ? v : 1);
    }
    __syncthreads();
    fcnt[tid] = fbase[tid];
    __syncthreads();
    for (int e = cbase + tid; e < cend; e += 256) {
        unsigned int pv = pairs[e];
        int p = atomicAdd(&fcnt[pv >> 16], 1);
        srcs[p] = (int)(pv & 0xFFFFu);
    }
}

__global__ void k_bsearch(const int* __restrict__ batch, int* __restrict__ boff,
                          int* __restrict__ offs) {
    int b = threadIdx.x;
    if (b <= Bb) {
        int lo = 0, hi = Nn;
        while (lo < hi) {
            int mid = (lo + hi) >> 1;
            if (batch[mid] < b) lo = mid + 1; else hi = mid;
        }
        boff[b] = lo;
    }
    if (b == 0) offs[Nn] = Ee;
}

// ---------------- weight prep (layers 2-4): fragment-ordered bf16 ----------------

template <int NOUT>
__global__ void k_prepW(const float* __restrict__ Wl, const float* __restrict__ Wr,
                        uint4* __restrict__ outw) {
    constexpr int NT = NOUT / 16;
    int G = blockIdx.x * 256 + threadIdx.x;
    int per = 2 * NT * 64;
    int S = G / per, rem = G % per;
    int lane = rem & 63, sT = rem >> 6;
    int s = sT / NT, T = sT % NT;
    int q = lane >> 4, m = lane & 15;
    int k0 = S * 64 + s * 32 + q * 8;
    int nc = T * 16 + m;
    union { uint4 u; unsigned short h[8]; } pk;
#pragma unroll
    for (int j = 0; j < 8; j++) {
        int kk = k0 + j;
        float wv = (kk < 256) ? Wl[kk * NOUT + nc] : Wr[(kk - 256) * NOUT + nc];
        pk.h[j] = f2bf(wv);
    }
    outw[G] = pk.u;
}

// layer 1: [Wl1(15) | 0 | Wr1(15) | 0] -> K=32 fragment order, NT=16 tiles
__global__ void k_prepW1(const float* __restrict__ Wl, const float* __restrict__ Wr,
                         uint4* __restrict__ outw) {
    int G = blockIdx.x * 256 + threadIdx.x;   // 0..1023
    int T = G >> 6, lane = G & 63;
    int q = lane >> 4, m = lane & 15;
    int nc = T * 16 + m;
    union { uint4 u; unsigned short h[8]; } pk;
#pragma unroll
    for (int j = 0; j < 8; j++) {
        int k = q * 8 + j;
        float wv;
        if (k < 15)       wv = Wl[k * HID + nc];
        else if (k == 15) wv = 0.0f;
        else if (k < 31)  wv = Wr[(k - 16) * HID + nc];
        else              wv = 0.0f;
        pk.h[j] = f2bf(wv);
    }
    outw[G] = pk.u;
}

// ---------------- layer-1 A build ----------------

__global__ void k_prep1(const float* __restrict__ x, const int* __restrict__ offs,
                        const int* __restrict__ srcs, const float* __restrict__ invc,
                        unsigned short* __restrict__ A1) {
    int node = blockIdx.x * 16 + (threadIdx.x >> 4);
    int f = threadIdx.x & 15;
    int s0 = offs[node], s1 = offs[node + 1];
    float acc = 0.0f;
    for (int i = s0; i < s1; i++) {
        int s = srcs[i];
        if (f < 15) acc += x[s * INF + f];
    }
    unsigned short mv = (f < 15) ? f2bf(acc * invc[node]) : (unsigned short)0;
    unsigned short xv = (f < 15) ? f2bf(x[(size_t)node * INF + f]) : (unsigned short)0;
    A1[(size_t)node * 32 + f] = mv;
    A1[(size_t)node * 32 + 16 + f] = xv;
}

// ---------------- aggregation (256-d bf16), 8 edges in flight ----------------

__device__ __forceinline__ void acc8(float* a, uint4 v) {
    a[0] += bflo(v.x); a[1] += bfhi(v.x);
    a[2] += bflo(v.y); a[3] += bfhi(v.y);
    a[4] += bflo(v.z); a[5] += bfhi(v.z);
    a[6] += bflo(v.w); a[7] += bfhi(v.w);
}

__global__ void k_agg256_bf(const uint4* __restrict__ h4, const int* __restrict__ offs,
                            const int* __restrict__ srcs, const float* __restrict__ invc,
                            uint4* __restrict__ mean4) {
    int node = blockIdx.x * 4 + (threadIdx.x >> 6);
    int lane = threadIdx.x & 63;
    int sub = lane >> 5, q = lane & 31;
    int s0 = offs[node], s1 = offs[node + 1];
    int deg = s1 - s0;
    int dcap = deg < 64 ? deg : 64;
    int myidx = (lane < deg) ? srcs[s0 + lane] : 0;
    float a[8] = {};
    int i = 0;
    for (; i + 8 <= dcap; i += 8) {
        int sA = __shfl(myidx, i + sub);
        int sB = __shfl(myidx, i + 2 + sub);
        int sC = __shfl(myidx, i + 4 + sub);
        int sD = __shfl(myidx, i + 6 + sub);
        uint4 vA = h4[(size_t)sA * 32 + q];
        uint4 vB = h4[(size_t)sB * 32 + q];
        uint4 vC = h4[(size_t)sC * 32 + q];
        uint4 vD = h4[(size_t)sD * 32 + q];
        acc8(a, vA); acc8(a, vB); acc8(a, vC); acc8(a, vD);
    }
    if (i + 4 <= dcap) {
        int sA = __shfl(myidx, i + sub);
        int sB = __shfl(myidx, i + 2 + sub);
        uint4 vA = h4[(size_t)sA * 32 + q];
        uint4 vB = h4[(size_t)sB * 32 + q];
        acc8(a, vA); acc8(a, vB);
        i += 4;
    }
    if (i + 2 <= dcap) {
        int sA = __shfl(myidx, i + sub);
        uint4 vA = h4[(size_t)sA * 32 + q];
        acc8(a, vA);
        i += 2;
    }
    if (i < dcap && sub == 0) {
        int sA = __shfl(myidx, i);
        uint4 vA = h4[(size_t)sA * 32 + q];
        acc8(a, vA);
    }
    for (int j = 64; j + 1 < deg; j += 2) {
        int s = srcs[s0 + j + sub];
        uint4 v = h4[(size_t)s * 32 + q];
        acc8(a, v);
    }
    if (deg > 64 && ((deg - 64) & 1) && sub == 0) {
        int s = srcs[s1 - 1];
        uint4 v = h4[(size_t)s * 32 + q];
        acc8(a, v);
    }
#pragma unroll
    for (int j = 0; j < 8; j++) a[j] += __shfl_xor(a[j], 32);
    if (sub == 0) {
        float ic = invc[node];
        uint4 o;
        o.x = (unsigned int)f2bf(a[0] * ic) | ((unsigned int)f2bf(a[1] * ic) << 16);
        o.y = (unsigned int)f2bf(a[2] * ic) | ((unsigned int)f2bf(a[3] * ic) << 16);
        o.z = (unsigned int)f2bf(a[4] * ic) | ((unsigned int)f2bf(a[5] * ic) << 16);
        o.w = (unsigned int)f2bf(a[6] * ic) | ((unsigned int)f2bf(a[7] * ic) << 16);
        mean4[(size_t)node * 32 + q] = o;
    }
}

// ---------------- MFMA GEMM v3: LDS-staged A (coalesced), B from L2, 3 barriers ----------------
// LDS layout: Abuf[row][chunk16] with row stride 33 uint4 (528 B). Odd uint4
// stride => b128 reads at (row=m, chunk=pp*4+q) hit banks 4(m+q)+d: natural
// 8-phase pattern, no extra conflicts. Staging: 8 coalesced uint4 loads/thread.

template <int NOUT, bool F32OUT>
__global__ __launch_bounds__(256) void k_gemm_mfma(
    const unsigned short* __restrict__ Am,
    const unsigned short* __restrict__ Ah,
    const uint4* __restrict__ Wfrag,
    const float* __restrict__ bias, const float* __restrict__ g,
    const float* __restrict__ bt, void* __restrict__ outp, int n) {
    constexpr int NT = NOUT / 16;
    constexpr int CT = NT / 4;
    constexpr int SROW = 33;                     // uint4 per LDS row
    __shared__ __align__(16) uint4 Abuf[64 * SROW];
    __shared__ float lnbuf[2][4][64];
    int tid = threadIdx.x;
    int w = tid >> 6, lane = tid & 63;
    int q = lane >> 4, m = lane & 15;
    int rowbase = blockIdx.x * 64;

    f32x4 acc[4][CT];
#pragma unroll
    for (int i = 0; i < 4; i++)
#pragma unroll
        for (int t = 0; t < CT; t++) acc[i][t] = (f32x4)0.f;

    union U { uint4 u; bf16x8 b; };
    U a[4], breg[2][CT];

    auto stage = [&](const unsigned short* A) {
        const uint4* Ag = (const uint4*)A + (size_t)rowbase * 32;
        uint4 v[8];
#pragma unroll
        for (int j = 0; j < 8; j++) {
            int c = j * 256 + tid;
            int row = c >> 5;
            v[j] = (rowbase + row < n) ? Ag[c] : make_uint4(0u, 0u, 0u, 0u);
        }
#pragma unroll
        for (int j = 0; j < 8; j++) {
            int c = j * 256 + tid;
            int row = c >> 5, kc = c & 31;
            Abuf[row * SROW + kc] = v[j];
        }
    };
    auto loadB = [&](int p, U* br) {
#pragma unroll
        for (int t = 0; t < CT; t++)
            br[t].u = Wfrag[(size_t)(p * NT + w * CT + t) * 64 + lane];
    };

    stage(Am);
    loadB(0, breg[0]);
    __syncthreads();

#pragma unroll
    for (int ph = 0; ph < 2; ph++) {
        if (ph == 1) {
            __syncthreads();     // all waves done reading mean tiles
            stage(Ah);
            __syncthreads();
        }
#pragma unroll
        for (int pp = 0; pp < 8; pp++) {
            int p = ph * 8 + pp;
            int cur = p & 1, nxt = cur ^ 1;
#pragma unroll
            for (int i = 0; i < 4; i++)
                a[i].u = Abuf[(i * 16 + m) * SROW + pp * 4 + q];
            if (p < 15) loadB(p + 1, breg[nxt]);
#pragma unroll
            for (int i = 0; i < 4; i++)
#pragma unroll
                for (int t = 0; t < CT; t++)
                    acc[i][t] = __builtin_amdgcn_mfma_f32_16x16x32_bf16(
                        a[i].b, breg[cur][t].b, acc[i][t], 0, 0, 0);
        }
    }

    int col0 = w * CT * 16;
    float bv[CT], gv[CT], btv[CT];
#pragma unroll
    for (int t = 0; t < CT; t++) {
        int c = col0 + t * 16 + m;
        bv[t] = bias[c]; gv[t] = g[c]; btv[t] = bt[c];
    }
#pragma unroll
    for (int i = 0; i < 4; i++) {
#pragma unroll
        for (int r = 0; r < 4; r++) {
            float s1 = 0.f, s2 = 0.f;
#pragma unroll
            for (int t = 0; t < CT; t++) {
                float v = acc[i][t][r] + bv[t];
                acc[i][t][r] = v;
                s1 += v; s2 += v * v;
            }
#pragma unroll
            for (int o = 1; o < 16; o <<= 1) {
                s1 += __shfl_xor(s1, o);
                s2 += __shfl_xor(s2, o);
            }
            if (m == 0) {
                int row = i * 16 + q * 4 + r;
                lnbuf[0][w][row] = s1;
                lnbuf[1][w][row] = s2;
            }
        }
    }
    __syncthreads();
#pragma unroll
    for (int i = 0; i < 4; i++) {
#pragma unroll
        for (int r = 0; r < 4; r++) {
            int rit = i * 16 + q * 4 + r;
            float ts1 = lnbuf[0][0][rit] + lnbuf[0][1][rit] + lnbuf[0][2][rit] + lnbuf[0][3][rit];
            float ts2 = lnbuf[1][0][rit] + lnbuf[1][1][rit] + lnbuf[1][2][rit] + lnbuf[1][3][rit];
            float mu  = ts1 * (1.0f / NOUT);
            float var = ts2 * (1.0f / NOUT) - mu * mu;
            float rs  = 1.0f / sqrtf(var + 1e-5f);
            int row = rowbase + rit;
            if (row < n) {
#pragma unroll
                for (int t = 0; t < CT; t++) {
                    int c = col0 + t * 16 + m;
                    float y = (acc[i][t][r] - mu) * rs * gv[t] + btv[t];
                    float res = gelu_f(y);
                    if (F32OUT) ((float*)outp)[(size_t)row * NOUT + c] = res;
                    else ((unsigned short*)outp)[(size_t)row * NOUT + c] = f2bf(res);
                }
            }
        }
    }
}

// ---------------- layer-1 MFMA GEMM: single K=32 step on A1, LN+GELU ----------------

__global__ __launch_bounds__(256) void k_gemm_mfma1(
    const unsigned short* __restrict__ A1, const uint4* __restrict__ Wfrag,
    const float* __restrict__ bias, const float* __restrict__ g,
    const float* __restrict__ bt, unsigned short* __restrict__ outp, int n) {
    constexpr int NT = 16, CT = 4;
    __shared__ float lnbuf[2][4][64];
    int tid = threadIdx.x;
    int w = tid >> 6, lane = tid & 63;
    int q = lane >> 4, m = lane & 15;
    int rowbase = blockIdx.x * 64;

    union U { uint4 u; bf16x8 b; };
    U a[4], b[CT];
#pragma unroll
    for (int i = 0; i < 4; i++) {
        int row = rowbase + i * 16 + m;
        a[i].u = (row < n) ? *(const uint4*)(A1 + (size_t)row * 32 + q * 8)
                           : make_uint4(0u, 0u, 0u, 0u);
    }
#pragma unroll
    for (int t = 0; t < CT; t++)
        b[t].u = Wfrag[(size_t)(w * CT + t) * 64 + lane];

    f32x4 acc[4][CT];
#pragma unroll
    for (int i = 0; i < 4; i++)
#pragma unroll
        for (int t = 0; t < CT; t++)
            acc[i][t] = __builtin_amdgcn_mfma_f32_16x16x32_bf16(
                a[i].b, b[t].b, (f32x4)0.f, 0, 0, 0);

    int col0 = w * CT * 16;
    float bv[CT], gv[CT], btv[CT];
#pragma unroll
    for (int t = 0; t < CT; t++) {
        int c = col0 + t * 16 + m;
        bv[t] = bias[c]; gv[t] = g[c]; btv[t] = bt[c];
    }
#pragma unroll
    for (int i = 0; i < 4; i++) {
#pragma unroll
        for (int r = 0; r < 4; r++) {
            float s1 = 0.f, s2 = 0.f;
#pragma unroll
            for (int t = 0; t < CT; t++) {
                float v = acc[i][t][r] + bv[t];
                acc[i][t][r] = v;
                s1 += v; s2 += v * v;
            }
#pragma unroll
            for (int o = 1; o < 16; o <<= 1) {
                s1 += __shfl_xor(s1, o);
                s2 += __shfl_xor(s2, o);
            }
            if (m == 0) {
                int row = i * 16 + q * 4 + r;
                lnbuf[0][w][row] = s1;
                lnbuf[1][w][row] = s2;
            }
        }
    }
    __syncthreads();
#pragma unroll
    for (int i = 0; i < 4; i++) {
#pragma unroll
        for (int r = 0; r < 4; r++) {
            int rit = i * 16 + q * 4 + r;
            float ts1 = lnbuf[0][0][rit] + lnbuf[0][1][rit] + lnbuf[0][2][rit] + lnbuf[0][3][rit];
            float ts2 = lnbuf[1][0][rit] + lnbuf[1][1][rit] + lnbuf[1][2][rit] + lnbuf[1][3][rit];
            float mu  = ts1 * (1.0f / HID);
            float var = ts2 * (1.0f / HID) - mu * mu;
            float rs  = 1.0f / sqrtf(var + 1e-5f);
            int row = rowbase + rit;
            if (row < n) {
#pragma unroll
                for (int t = 0; t < CT; t++) {
                    int c = col0 + t * 16 + m;
                    float y = (acc[i][t][r] - mu) * rs * gv[t] + btv[t];
                    outp[(size_t)row * HID + c] = f2bf(gelu_f(y));
                }
            }
        }
    }
}

// ---------------- pool ----------------

__global__ __launch_bounds__(1024) void k_pool(const float* __restrict__ h,
                                               const int* __restrict__ boff,
                                               float* __restrict__ out) {
    __shared__ float red[8][128];
    int b = blockIdx.x, tid = threadIdx.x;
    int j = tid & 127, grp = tid >> 7;
    int s0 = boff[b], s1 = boff[b + 1];
    float a0 = 0.f, a1 = 0.f, a2 = 0.f, a3 = 0.f;
    int i = s0 + grp;
    for (; i + 24 < s1; i += 32) {
        a0 += h[(size_t)i * OUTF + j];
        a1 += h[(size_t)(i + 8) * OUTF + j];
        a2 += h[(size_t)(i + 16) * OUTF + j];
        a3 += h[(size_t)(i + 24) * OUTF + j];
    }
    for (; i < s1; i += 8) a0 += h[(size_t)i * OUTF + j];
    red[grp][j] = (a0 + a1) + (a2 + a3);
    __syncthreads();
    if (tid < 128) {
        float s = ((red[0][tid] + red[1][tid]) + (red[2][tid] + red[3][tid]))
                + ((red[4][tid] + red[5][tid]) + (red[6][tid] + red[7][tid]));
        int c = s1 - s0;
        out[b * OUTF + tid] = s / fmaxf((float)c, 1.0f);
    }
}

// ---------------- launch ----------------

extern "C" void kernel_launch(void* const* d_in, const int* in_sizes, int n_in,
                              void* d_out, int out_size, void* d_ws, size_t ws_size,
                              hipStream_t stream) {
    const float* x     = (const float*)d_in[0];
    const int*   ei    = (const int*)d_in[1];
    const int*   src   = ei;
    const int*   dst   = ei + Ee;
    const int*   batch = (const int*)d_in[2];
    const float* Wl1 = (const float*)d_in[3];
    const float* Wr1 = (const float*)d_in[4];
    const float* b1  = (const float*)d_in[5];
    const float* g1  = (const float*)d_in[6];
    const float* bt1 = (const float*)d_in[7];
    const float* Wl2 = (const float*)d_in[8];
    const float* Wr2 = (const float*)d_in[9];
    const float* b2  = (const float*)d_in[10];
    const float* g2  = (const float*)d_in[11];
    const float* bt2 = (const float*)d_in[12];
    const float* Wl3 = (const float*)d_in[13];
    const float* Wr3 = (const float*)d_in[14];
    const float* b3  = (const float*)d_in[15];
    const float* g3  = (const float*)d_in[16];
    const float* bt3 = (const float*)d_in[17];
    const float* Wl4 = (const float*)d_in[18];
    const float* Wr4 = (const float*)d_in[19];
    const float* b4  = (const float*)d_in[20];
    const float* g4  = (const float*)d_in[21];
    const float* bt4 = (const float*)d_in[22];
    float* out = (float*)d_out;

    char* ws = (char*)d_ws;
    size_t off = 0;
    auto alloc = [&](size_t bytes) -> char* {
        char* p = ws + off;
        off = (off + bytes + 255) & ~(size_t)255;
        return p;
    };
    int*   offs    = (int*)alloc((size_t)(Nn + 1) * 4);
    int*   srcs    = (int*)alloc((size_t)Ee * 4);
    float* invc    = (float*)alloc((size_t)Nn * 4);
    int*   boff    = (int*)alloc((size_t)(Bb + 1) * 4);
    unsigned int* pairs = (unsigned int*)alloc((size_t)Ee * 4);
    int*   Gcnt    = (int*)alloc((size_t)SCANN * 4);
    int*   Goff    = (int*)alloc((size_t)SCANN * 4);
    int*   partial = (int*)alloc(256 * 4);
    unsigned short* A1    = (unsigned short*)alloc((size_t)Nn * 32 * 2);
    unsigned short* meanb = (unsigned short*)alloc((size_t)Nn * HID * 2);
    unsigned short* hA    = (unsigned short*)alloc((size_t)Nn * HID * 2);
    unsigned short* hB    = (unsigned short*)alloc((size_t)Nn * HID * 2);
    float* hOut    = (float*)alloc((size_t)Nn * OUTF * 4);
    uint4* W1f     = (uint4*)alloc((size_t)32 * HID * 2);
    uint4* W2f     = (uint4*)alloc((size_t)512 * HID * 2);
    uint4* W3f     = (uint4*)alloc((size_t)512 * HID * 2);
    uint4* W4f     = (uint4*)alloc((size_t)512 * OUTF * 2);

    int nbScan = (SCANN + 255) / 256;
    k_sortA<<<NB1, 256, 0, stream>>>(dst, Gcnt);
    k_gscan_partial<<<nbScan, 256, 0, stream>>>(Gcnt, partial, SCANN);
    k_gscan_mid<<<1, 256, 0, stream>>>(partial, nbScan);
    k_gscan_final<<<nbScan, 256, 0, stream>>>(Gcnt, partial, Goff, SCANN);
    k_sortC<<<NB1, 256, 0, stream>>>(dst, src, Goff, pairs);
    k_sortD<<<NCB, 256, 0, stream>>>(pairs, Goff, offs, srcs, invc);
    k_bsearch<<<1, 256, 0, stream>>>(batch, boff, offs);

    k_prepW1<<<4, 256, 0, stream>>>(Wl1, Wr1, W1f);
    k_prepW<256><<<64, 256, 0, stream>>>(Wl2, Wr2, W2f);
    k_prepW<256><<<64, 256, 0, stream>>>(Wl3, Wr3, W3f);
    k_prepW<128><<<32, 256, 0, stream>>>(Wl4, Wr4, W4f);

    int gb = (Nn + 63) / 64;
    // layer 1 (MFMA, K=32)
    k_prep1<<<Nn / 16, 256, 0, stream>>>(x, offs, srcs, invc, A1);
    k_gemm_mfma1<<<gb, 256, 0, stream>>>(A1, W1f, b1, g1, bt1, hA, Nn);
    // layer 2
    k_agg256_bf<<<Nn / 4, 256, 0, stream>>>((const uint4*)hA, offs, srcs, invc, (uint4*)meanb);
    k_gemm_mfma<256, false><<<gb, 256, 0, stream>>>(meanb, hA, W2f, b2, g2, bt2, hB, Nn);
    // layer 3
    k_agg256_bf<<<Nn / 4, 256, 0, stream>>>((const uint4*)hB, offs, srcs, invc, (uint4*)meanb);
    k_gemm_mfma<256, false><<<gb, 256, 0, stream>>>(meanb, hB, W3f, b3, g3, bt3, hA, Nn);
    // layer 4
    k_agg256_bf<<<Nn / 4, 256, 0, stream>>>((const uint4*)hA, offs, srcs, invc, (uint4*)meanb);
    k_gemm_mfma<128, true><<<gb, 256, 0, stream>>>(meanb, hA, W4f, b4, g4, bt4, hOut, Nn);
    // pool
    k_pool<<<Bb, 1024, 0, stream>>>(hOut, boff, out);
}

// Round 10
// 479.170 us; speedup vs baseline: 3.0300x; 1.0717x over previous
//
#include <hip/hip_runtime.h>
#include <math.h>

constexpr int Nn   = 50000;
constexpr int Ee   = 800000;
constexpr int Bb   = 128;
constexpr int INF  = 15;
constexpr int HID  = 256;
constexpr int OUTF = 128;

constexpr int NCB   = (Nn + 255) / 256;   // 196 coarse buckets (dst>>8)
constexpr int CHUNK = 4096;
constexpr int NB1   = (Ee + CHUNK - 1) / CHUNK;  // 196 sort blocks
constexpr int SCANN = NCB * NB1;          // 38416

typedef __attribute__((ext_vector_type(8))) __bf16 bf16x8;
typedef __attribute__((ext_vector_type(4))) float  f32x4;

// gelu(v) = 0.5 v (1 + erf(v/sqrt2)); erf via A&S 7.1.26 (max err 1.5e-7, sub-bf16-ulp).
// NOTE: argument scaling by 1/sqrt2 happens HERE (R8/R9 bug: it was missing).
__device__ __forceinline__ float gelu_f(float v) {
    float s = fabsf(v) * 0.7071067811865475f;
    float t = __builtin_amdgcn_rcpf(fmaf(0.3275911f, s, 1.0f));
    float p = fmaf(fmaf(fmaf(fmaf(1.061405429f, t, -1.453152027f),
                             t, 1.421413741f), t, -0.284496736f), t, 0.254829592f) * t;
    float e = __expf(-s * s);
    float er = copysignf(1.0f - p * e, v);
    return 0.5f * v * (1.0f + er);
}

__device__ __forceinline__ unsigned short f2bf(float f) {
    union { float f; unsigned int u; } v; v.f = f;
    unsigned int r = v.u + 0x7fffu + ((v.u >> 16) & 1u);   // RNE
    return (unsigned short)(r >> 16);
}

__device__ __forceinline__ float bflo(unsigned int p) { return __uint_as_float(p << 16); }
__device__ __forceinline__ float bfhi(unsigned int p) { return __uint_as_float(p & 0xffff0000u); }

// ---------------- CSR build: two-level counting sort (LDS atomics only) ----------------

__global__ void k_sortA(const int* __restrict__ dst, int* __restrict__ Gcnt) {
    __shared__ int cnt[NCB];
    int tid = threadIdx.x, blk = blockIdx.x;
    for (int i = tid; i < NCB; i += 256) cnt[i] = 0;
    __syncthreads();
    int base = blk * CHUNK;
    for (int i = 0; i < CHUNK; i += 256) {
        int e = base + i + tid;
        if (e < Ee) atomicAdd(&cnt[dst[e] >> 8], 1);
    }
    __syncthreads();
    for (int i = tid; i < NCB; i += 256) Gcnt[i * NB1 + blk] = cnt[i];
}

__global__ void k_gscan_partial(const int* __restrict__ in, int* __restrict__ partial, int n) {
    __shared__ int s[256];
    int tid = threadIdx.x, i = blockIdx.x * 256 + tid;
    s[tid] = (i < n) ? in[i] : 0;
    __syncthreads();
    for (int off = 128; off; off >>= 1) {
        if (tid < off) s[tid] += s[tid + off];
        __syncthreads();
    }
    if (tid == 0) partial[blockIdx.x] = s[0];
}

__global__ void k_gscan_mid(int* __restrict__ partial, int nb) {
    __shared__ int s[256];
    int tid = threadIdx.x;
    int v = (tid < nb) ? partial[tid] : 0;
    s[tid] = v;
    __syncthreads();
    for (int off = 1; off < 256; off <<= 1) {
        int t = (tid >= off) ? s[tid - off] : 0;
        __syncthreads();
        s[tid] += t;
        __syncthreads();
    }
    if (tid < nb) partial[tid] = s[tid] - v;
}

__global__ void k_gscan_final(const int* __restrict__ in, const int* __restrict__ partial,
                              int* __restrict__ out, int n) {
    __shared__ int s[256];
    int tid = threadIdx.x, i = blockIdx.x * 256 + tid;
    int v = (i < n) ? in[i] : 0;
    s[tid] = v;
    __syncthreads();
    for (int off = 1; off < 256; off <<= 1) {
        int t = (tid >= off) ? s[tid - off] : 0;
        __syncthreads();
        s[tid] += t;
        __syncthreads();
    }
    if (i < n) out[i] = s[tid] - v + partial[blockIdx.x];
}

__global__ void k_sortC(const int* __restrict__ dst, const int* __restrict__ srcv,
                        const int* __restrict__ Goff, unsigned int* __restrict__ pairs) {
    __shared__ int cur[NCB];
    int tid = threadIdx.x, blk = blockIdx.x;
    for (int i = tid; i < NCB; i += 256) cur[i] = Goff[i * NB1 + blk];
    __syncthreads();
    int base = blk * CHUNK;
    for (int i = 0; i < CHUNK; i += 256) {
        int e = base + i + tid;
        if (e < Ee) {
            int d = dst[e];
            int p = atomicAdd(&cur[d >> 8], 1);
            pairs[p] = ((unsigned int)(d & 255) << 16) | (unsigned int)srcv[e];
        }
    }
}

__global__ void k_sortD(const unsigned int* __restrict__ pairs, const int* __restrict__ Goff,
                        int* __restrict__ offs, int* __restrict__ srcs, float* __restrict__ invc) {
    __shared__ int fcnt[256];
    __shared__ int fbase[256];
    __shared__ int s[256];
    int tid = threadIdx.x, cb = blockIdx.x;
    int cbase = Goff[cb * NB1];
    int cend = (cb + 1 < NCB) ? Goff[(cb + 1) * NB1] : Ee;
    fcnt[tid] = 0;
    __syncthreads();
    for (int e = cbase + tid; e < cend; e += 256)
        atomicAdd(&fcnt[pairs[e] >> 16], 1);
    __syncthreads();
    int v = fcnt[tid];
    s[tid] = v;
    __syncthreads();
    for (int off = 1; off < 256; off <<= 1) {
        int t = (tid >= off) ? s[tid - off] : 0;
        __syncthreads();
        s[tid] += t;
        __syncthreads();
    }
    fbase[tid] = cbase + s[tid] - v;
    int node = cb * 256 + tid;
    if (node < Nn) {
        offs[node] = fbase[tid];
        invc[node] = 1.0f / (float)(v > 1 ? v : 1);
    }
    __syncthreads();
    fcnt[tid] = fbase[tid];
    __syncthreads();
    for (int e = cbase + tid; e < cend; e += 256) {
        unsigned int pv = pairs[e];
        int p = atomicAdd(&fcnt[pv >> 16], 1);
        srcs[p] = (int)(pv & 0xFFFFu);
    }
}

__global__ void k_bsearch(const int* __restrict__ batch, int* __restrict__ boff,
                          int* __restrict__ offs) {
    int b = threadIdx.x;
    if (b <= Bb) {
        int lo = 0, hi = Nn;
        while (lo < hi) {
            int mid = (lo + hi) >> 1;
            if (batch[mid] < b) lo = mid + 1; else hi = mid;
        }
        boff[b] = lo;
    }
    if (b == 0) offs[Nn] = Ee;
}

// ---------------- weight prep (layers 2-4): fragment-ordered bf16 ----------------

template <int NOUT>
__global__ void k_prepW(const float* __restrict__ Wl, const float* __restrict__ Wr,
                        uint4* __restrict__ outw) {
    constexpr int NT = NOUT / 16;
    int G = blockIdx.x * 256 + threadIdx.x;
    int per = 2 * NT * 64;
    int S = G / per, rem = G % per;
    int lane = rem & 63, sT = rem >> 6;
    int s = sT / NT, T = sT % NT;
    int q = lane >> 4, m = lane & 15;
    int k0 = S * 64 + s * 32 + q * 8;
    int nc = T * 16 + m;
    union { uint4 u; unsigned short h[8]; } pk;
#pragma unroll
    for (int j = 0; j < 8; j++) {
        int kk = k0 + j;
        float wv = (kk < 256) ? Wl[kk * NOUT + nc] : Wr[(kk - 256) * NOUT + nc];
        pk.h[j] = f2bf(wv);
    }
    outw[G] = pk.u;
}

// layer 1: [Wl1(15) | 0 | Wr1(15) | 0] -> K=32 fragment order, NT=16 tiles
__global__ void k_prepW1(const float* __restrict__ Wl, const float* __restrict__ Wr,
                         uint4* __restrict__ outw) {
    int G = blockIdx.x * 256 + threadIdx.x;   // 0..1023
    int T = G >> 6, lane = G & 63;
    int q = lane >> 4, m = lane & 15;
    int nc = T * 16 + m;
    union { uint4 u; unsigned short h[8]; } pk;
#pragma unroll
    for (int j = 0; j < 8; j++) {
        int k = q * 8 + j;
        float wv;
        if (k < 15)       wv = Wl[k * HID + nc];
        else if (k == 15) wv = 0.0f;
        else if (k < 31)  wv = Wr[(k - 16) * HID + nc];
        else              wv = 0.0f;
        pk.h[j] = f2bf(wv);
    }
    outw[G] = pk.u;
}

// ---------------- layer-1 A build ----------------

__global__ void k_prep1(const float* __restrict__ x, const int* __restrict__ offs,
                        const int* __restrict__ srcs, const float* __restrict__ invc,
                        unsigned short* __restrict__ A1) {
    int node = blockIdx.x * 16 + (threadIdx.x >> 4);
    int f = threadIdx.x & 15;
    int s0 = offs[node], s1 = offs[node + 1];
    float acc = 0.0f;
    for (int i = s0; i < s1; i++) {
        int s = srcs[i];
        if (f < 15) acc += x[s * INF + f];
    }
    unsigned short mv = (f < 15) ? f2bf(acc * invc[node]) : (unsigned short)0;
    unsigned short xv = (f < 15) ? f2bf(x[(size_t)node * INF + f]) : (unsigned short)0;
    A1[(size_t)node * 32 + f] = mv;
    A1[(size_t)node * 32 + 16 + f] = xv;
}

// ---------------- aggregation (256-d bf16), 8 edges in flight ----------------

__device__ __forceinline__ void acc8(float* a, uint4 v) {
    a[0] += bflo(v.x); a[1] += bfhi(v.x);
    a[2] += bflo(v.y); a[3] += bfhi(v.y);
    a[4] += bflo(v.z); a[5] += bfhi(v.z);
    a[6] += bflo(v.w); a[7] += bfhi(v.w);
}

__global__ void k_agg256_bf(const uint4* __restrict__ h4, const int* __restrict__ offs,
                            const int* __restrict__ srcs, const float* __restrict__ invc,
                            uint4* __restrict__ mean4) {
    int node = blockIdx.x * 4 + (threadIdx.x >> 6);
    int lane = threadIdx.x & 63;
    int sub = lane >> 5, q = lane & 31;
    int s0 = offs[node], s1 = offs[node + 1];
    int deg = s1 - s0;
    int dcap = deg < 64 ? deg : 64;
    int myidx = (lane < deg) ? srcs[s0 + lane] : 0;
    float a[8] = {};
    int i = 0;
    for (; i + 8 <= dcap; i += 8) {
        int sA = __shfl(myidx, i + sub);
        int sB = __shfl(myidx, i + 2 + sub);
        int sC = __shfl(myidx, i + 4 + sub);
        int sD = __shfl(myidx, i + 6 + sub);
        uint4 vA = h4[(size_t)sA * 32 + q];
        uint4 vB = h4[(size_t)sB * 32 + q];
        uint4 vC = h4[(size_t)sC * 32 + q];
        uint4 vD = h4[(size_t)sD * 32 + q];
        acc8(a, vA); acc8(a, vB); acc8(a, vC); acc8(a, vD);
    }
    if (i + 4 <= dcap) {
        int sA = __shfl(myidx, i + sub);
        int sB = __shfl(myidx, i + 2 + sub);
        uint4 vA = h4[(size_t)sA * 32 + q];
        uint4 vB = h4[(size_t)sB * 32 + q];
        acc8(a, vA); acc8(a, vB);
        i += 4;
    }
    if (i + 2 <= dcap) {
        int sA = __shfl(myidx, i + sub);
        uint4 vA = h4[(size_t)sA * 32 + q];
        acc8(a, vA);
        i += 2;
    }
    if (i < dcap && sub == 0) {
        int sA = __shfl(myidx, i);
        uint4 vA = h4[(size_t)sA * 32 + q];
        acc8(a, vA);
    }
    for (int j = 64; j + 1 < deg; j += 2) {
        int s = srcs[s0 + j + sub];
        uint4 v = h4[(size_t)s * 32 + q];
        acc8(a, v);
    }
    if (deg > 64 && ((deg - 64) & 1) && sub == 0) {
        int s = srcs[s1 - 1];
        uint4 v = h4[(size_t)s * 32 + q];
        acc8(a, v);
    }
#pragma unroll
    for (int j = 0; j < 8; j++) a[j] += __shfl_xor(a[j], 32);
    if (sub == 0) {
        float ic = invc[node];
        uint4 o;
        o.x = (unsigned int)f2bf(a[0] * ic) | ((unsigned int)f2bf(a[1] * ic) << 16);
        o.y = (unsigned int)f2bf(a[2] * ic) | ((unsigned int)f2bf(a[3] * ic) << 16);
        o.z = (unsigned int)f2bf(a[4] * ic) | ((unsigned int)f2bf(a[5] * ic) << 16);
        o.w = (unsigned int)f2bf(a[6] * ic) | ((unsigned int)f2bf(a[7] * ic) << 16);
        mean4[(size_t)node * 32 + q] = o;
    }
}

// ---------------- MFMA GEMM v4: LDS-staged A, rolling-3 B prefetch (dist 2) ----------------

template <int NOUT, bool F32OUT>
__global__ __launch_bounds__(256) void k_gemm_mfma(
    const unsigned short* __restrict__ Am,
    const unsigned short* __restrict__ Ah,
    const uint4* __restrict__ Wfrag,
    const float* __restrict__ bias, const float* __restrict__ g,
    const float* __restrict__ bt, void* __restrict__ outp, int n) {
    constexpr int NT = NOUT / 16;
    constexpr int CT = NT / 4;
    constexpr int SROW = 33;                     // uint4 per LDS row
    __shared__ __align__(16) uint4 Abuf[64 * SROW];
    __shared__ float lnbuf[2][4][64];
    int tid = threadIdx.x;
    int w = tid >> 6, lane = tid & 63;
    int q = lane >> 4, m = lane & 15;
    int rowbase = blockIdx.x * 64;

    f32x4 acc[4][CT];
#pragma unroll
    for (int i = 0; i < 4; i++)
#pragma unroll
        for (int t = 0; t < CT; t++) acc[i][t] = (f32x4)0.f;

    union U { uint4 u; bf16x8 b; };
    U a[4], breg[3][CT];

    auto stage = [&](const unsigned short* A) {
        const uint4* Ag = (const uint4*)A + (size_t)rowbase * 32;
        uint4 v[8];
#pragma unroll
        for (int j = 0; j < 8; j++) {
            int c = j * 256 + tid;
            int row = c >> 5;
            v[j] = (rowbase + row < n) ? Ag[c] : make_uint4(0u, 0u, 0u, 0u);
        }
#pragma unroll
        for (int j = 0; j < 8; j++) {
            int c = j * 256 + tid;
            int row = c >> 5, kc = c & 31;
            Abuf[row * SROW + kc] = v[j];
        }
    };
    auto loadB = [&](int p, U* br) {
#pragma unroll
        for (int t = 0; t < CT; t++)
            br[t].u = Wfrag[(size_t)(p * NT + w * CT + t) * 64 + lane];
    };

    stage(Am);
    loadB(0, breg[0]);
    loadB(1, breg[1]);
    __syncthreads();

#pragma unroll
    for (int ph = 0; ph < 2; ph++) {
        if (ph == 1) {
            __syncthreads();     // all waves done reading mean tiles
            stage(Ah);
            __syncthreads();
        }
#pragma unroll
        for (int pp = 0; pp < 8; pp++) {
            int p = ph * 8 + pp;
            if (p + 2 < 16) loadB(p + 2, breg[(p + 2) % 3]);
#pragma unroll
            for (int i = 0; i < 4; i++)
                a[i].u = Abuf[(i * 16 + m) * SROW + pp * 4 + q];
#pragma unroll
            for (int i = 0; i < 4; i++)
#pragma unroll
                for (int t = 0; t < CT; t++)
                    acc[i][t] = __builtin_amdgcn_mfma_f32_16x16x32_bf16(
                        a[i].b, breg[p % 3][t].b, acc[i][t], 0, 0, 0);
        }
    }

    int col0 = w * CT * 16;
    float bv[CT], gv[CT], btv[CT];
#pragma unroll
    for (int t = 0; t < CT; t++) {
        int c = col0 + t * 16 + m;
        bv[t] = bias[c]; gv[t] = g[c]; btv[t] = bt[c];
    }
#pragma unroll
    for (int i = 0; i < 4; i++) {
#pragma unroll
        for (int r = 0; r < 4; r++) {
            float s1 = 0.f, s2 = 0.f;
#pragma unroll
            for (int t = 0; t < CT; t++) {
                float v = acc[i][t][r] + bv[t];
                acc[i][t][r] = v;
                s1 += v; s2 += v * v;
            }
#pragma unroll
            for (int o = 1; o < 16; o <<= 1) {
                s1 += __shfl_xor(s1, o);
                s2 += __shfl_xor(s2, o);
            }
            if (m == 0) {
                int row = i * 16 + q * 4 + r;
                lnbuf[0][w][row] = s1;
                lnbuf[1][w][row] = s2;
            }
        }
    }
    __syncthreads();
#pragma unroll
    for (int i = 0; i < 4; i++) {
#pragma unroll
        for (int r = 0; r < 4; r++) {
            int rit = i * 16 + q * 4 + r;
            float ts1 = lnbuf[0][0][rit] + lnbuf[0][1][rit] + lnbuf[0][2][rit] + lnbuf[0][3][rit];
            float ts2 = lnbuf[1][0][rit] + lnbuf[1][1][rit] + lnbuf[1][2][rit] + lnbuf[1][3][rit];
            float mu  = ts1 * (1.0f / NOUT);
            float var = ts2 * (1.0f / NOUT) - mu * mu;
            float rs  = 1.0f / sqrtf(var + 1e-5f);
            int row = rowbase + rit;
            if (row < n) {
#pragma unroll
                for (int t = 0; t < CT; t++) {
                    int c = col0 + t * 16 + m;
                    float y = (acc[i][t][r] - mu) * rs * gv[t] + btv[t];
                    float res = gelu_f(y);
                    if (F32OUT) ((float*)outp)[(size_t)row * NOUT + c] = res;
                    else ((unsigned short*)outp)[(size_t)row * NOUT + c] = f2bf(res);
                }
            }
        }
    }
}

// ---------------- layer-1 MFMA GEMM: single K=32 step on A1, LN+GELU ----------------

__global__ __launch_bounds__(256) void k_gemm_mfma1(
    const unsigned short* __restrict__ A1, const uint4* __restrict__ Wfrag,
    const float* __restrict__ bias, const float* __restrict__ g,
    const float* __restrict__ bt, unsigned short* __restrict__ outp, int n) {
    constexpr int NT = 16, CT = 4;
    __shared__ float lnbuf[2][4][64];
    int tid = threadIdx.x;
    int w = tid >> 6, lane = tid & 63;
    int q = lane >> 4, m = lane & 15;
    int rowbase = blockIdx.x * 64;

    union U { uint4 u; bf16x8 b; };
    U a[4], b[CT];
#pragma unroll
    for (int i = 0; i < 4; i++) {
        int row = rowbase + i * 16 + m;
        a[i].u = (row < n) ? *(const uint4*)(A1 + (size_t)row * 32 + q * 8)
                           : make_uint4(0u, 0u, 0u, 0u);
    }
#pragma unroll
    for (int t = 0; t < CT; t++)
        b[t].u = Wfrag[(size_t)(w * CT + t) * 64 + lane];

    f32x4 acc[4][CT];
#pragma unroll
    for (int i = 0; i < 4; i++)
#pragma unroll
        for (int t = 0; t < CT; t++)
            acc[i][t] = __builtin_amdgcn_mfma_f32_16x16x32_bf16(
                a[i].b, b[t].b, (f32x4)0.f, 0, 0, 0);

    int col0 = w * CT * 16;
    float bv[CT], gv[CT], btv[CT];
#pragma unroll
    for (int t = 0; t < CT; t++) {
        int c = col0 + t * 16 + m;
        bv[t] = bias[c]; gv[t] = g[c]; btv[t] = bt[c];
    }
#pragma unroll
    for (int i = 0; i < 4; i++) {
#pragma unroll
        for (int r = 0; r < 4; r++) {
            float s1 = 0.f, s2 = 0.f;
#pragma unroll
            for (int t = 0; t < CT; t++) {
                float v = acc[i][t][r] + bv[t];
                acc[i][t][r] = v;
                s1 += v; s2 += v * v;
            }
#pragma unroll
            for (int o = 1; o < 16; o <<= 1) {
                s1 += __shfl_xor(s1, o);
                s2 += __shfl_xor(s2, o);
            }
            if (m == 0) {
                int row = i * 16 + q * 4 + r;
                lnbuf[0][w][row] = s1;
                lnbuf[1][w][row] = s2;
            }
        }
    }
    __syncthreads();
#pragma unroll
    for (int i = 0; i < 4; i++) {
#pragma unroll
        for (int r = 0; r < 4; r++) {
            int rit = i * 16 + q * 4 + r;
            float ts1 = lnbuf[0][0][rit] + lnbuf[0][1][rit] + lnbuf[0][2][rit] + lnbuf[0][3][rit];
            float ts2 = lnbuf[1][0][rit] + lnbuf[1][1][rit] + lnbuf[1][2][rit] + lnbuf[1][3][rit];
            float mu  = ts1 * (1.0f / HID);
            float var = ts2 * (1.0f / HID) - mu * mu;
            float rs  = 1.0f / sqrtf(var + 1e-5f);
            int row = rowbase + rit;
            if (row < n) {
#pragma unroll
                for (int t = 0; t < CT; t++) {
                    int c = col0 + t * 16 + m;
                    float y = (acc[i][t][r] - mu) * rs * gv[t] + btv[t];
                    outp[(size_t)row * HID + c] = f2bf(gelu_f(y));
                }
            }
        }
    }
}

// ---------------- pool ----------------

__global__ __launch_bounds__(1024) void k_pool(const float* __restrict__ h,
                                               const int* __restrict__ boff,
                                               float* __restrict__ out) {
    __shared__ float red[8][128];
    int b = blockIdx.x, tid = threadIdx.x;
    int j = tid & 127, grp = tid >> 7;
    int s0 = boff[b], s1 = boff[b + 1];
    float a0 = 0.f, a1 = 0.f, a2 = 0.f, a3 = 0.f;
    int i = s0 + grp;
    for (; i + 24 < s1; i += 32) {
        a0 += h[(size_t)i * OUTF + j];
        a1 += h[(size_t)(i + 8) * OUTF + j];
        a2 += h[(size_t)(i + 16) * OUTF + j];
        a3 += h[(size_t)(i + 24) * OUTF + j];
    }
    for (; i < s1; i += 8) a0 += h[(size_t)i * OUTF + j];
    red[grp][j] = (a0 + a1) + (a2 + a3);
    __syncthreads();
    if (tid < 128) {
        float s = ((red[0][tid] + red[1][tid]) + (red[2][tid] + red[3][tid]))
                + ((red[4][tid] + red[5][tid]) + (red[6][tid] + red[7][tid]));
        int c = s1 - s0;
        out[b * OUTF + tid] = s / fmaxf((float)c, 1.0f);
    }
}

// ---------------- launch ----------------

extern "C" void kernel_launch(void* const* d_in, const int* in_sizes, int n_in,
                              void* d_out, int out_size, void* d_ws, size_t ws_size,
                              hipStream_t stream) {
    const float* x     = (const float*)d_in[0];
    const int*   ei    = (const int*)d_in[1];
    const int*   src   = ei;
    const int*   dst   = ei + Ee;
    const int*   batch = (const int*)d_in[2];
    const float* Wl1 = (const float*)d_in[3];
    const float* Wr1 = (const float*)d_in[4];
    const float* b1  = (const float*)d_in[5];
    const float* g1  = (const float*)d_in[6];
    const float* bt1 = (const float*)d_in[7];
    const float* Wl2 = (const float*)d_in[8];
    const float* Wr2 = (const float*)d_in[9];
    const float* b2  = (const float*)d_in[10];
    const float* g2  = (const float*)d_in[11];
    const float* bt2 = (const float*)d_in[12];
    const float* Wl3 = (const float*)d_in[13];
    const float* Wr3 = (const float*)d_in[14];
    const float* b3  = (const float*)d_in[15];
    const float* g3  = (const float*)d_in[16];
    const float* bt3 = (const float*)d_in[17];
    const float* Wl4 = (const float*)d_in[18];
    const float* Wr4 = (const float*)d_in[19];
    const float* b4  = (const float*)d_in[20];
    const float* g4  = (const float*)d_in[21];
    const float* bt4 = (const float*)d_in[22];
    float* out = (float*)d_out;

    char* ws = (char*)d_ws;
    size_t off = 0;
    auto alloc = [&](size_t bytes) -> char* {
        char* p = ws + off;
        off = (off + bytes + 255) & ~(size_t)255;
        return p;
    };
    int*   offs    = (int*)alloc((size_t)(Nn + 1) * 4);
    int*   srcs    = (int*)alloc((size_t)Ee * 4);
    float* invc    = (float*)alloc((size_t)Nn * 4);
    int*   boff    = (int*)alloc((size_t)(Bb + 1) * 4);
    unsigned int* pairs = (unsigned int*)alloc((size_t)Ee * 4);
    int*   Gcnt    = (int*)alloc((size_t)SCANN * 4);
    int*   Goff    = (int*)alloc((size_t)SCANN * 4);
    int*   partial = (int*)alloc(256 * 4);
    unsigned short* A1    = (unsigned short*)alloc((size_t)Nn * 32 * 2);
    unsigned short* meanb = (unsigned short*)alloc((size_t)Nn * HID * 2);
    unsigned short* hA    = (unsigned short*)alloc((size_t)Nn * HID * 2);
    unsigned short* hB    = (unsigned short*)alloc((size_t)Nn * HID * 2);
    float* hOut    = (float*)alloc((size_t)Nn * OUTF * 4);
    uint4* W1f     = (uint4*)alloc((size_t)32 * HID * 2);
    uint4* W2f     = (uint4*)alloc((size_t)512 * HID * 2);
    uint4* W3f     = (uint4*)alloc((size_t)512 * HID * 2);
    uint4* W4f     = (uint4*)alloc((size_t)512 * OUTF * 2);

    int nbScan = (SCANN + 255) / 256;
    k_sortA<<<NB1, 256, 0, stream>>>(dst, Gcnt);
    k_gscan_partial<<<nbScan, 256, 0, stream>>>(Gcnt, partial, SCANN);
    k_gscan_mid<<<1, 256, 0, stream>>>(partial, nbScan);
    k_gscan_final<<<nbScan, 256, 0, stream>>>(Gcnt, partial, Goff, SCANN);
    k_sortC<<<NB1, 256, 0, stream>>>(dst, src, Goff, pairs);
    k_sortD<<<NCB, 256, 0, stream>>>(pairs, Goff, offs, srcs, invc);
    k_bsearch<<<1, 256, 0, stream>>>(batch, boff, offs);

    k_prepW1<<<4, 256, 0, stream>>>(Wl1, Wr1, W1f);
    k_prepW<256><<<64, 256, 0, stream>>>(Wl2, Wr2, W2f);
    k_prepW<256><<<64, 256, 0, stream>>>(Wl3, Wr3, W3f);
    k_prepW<128><<<32, 256, 0, stream>>>(Wl4, Wr4, W4f);

    int gb = (Nn + 63) / 64;
    // layer 1 (MFMA, K=32)
    k_prep1<<<Nn / 16, 256, 0, stream>>>(x, offs, srcs, invc, A1);
    k_gemm_mfma1<<<gb, 256, 0, stream>>>(A1, W1f, b1, g1, bt1, hA, Nn);
    // layer 2
    k_agg256_bf<<<Nn / 4, 256, 0, stream>>>((const uint4*)hA, offs, srcs, invc, (uint4*)meanb);
    k_gemm_mfma<256, false><<<gb, 256, 0, stream>>>(meanb, hA, W2f, b2, g2, bt2, hB, Nn);
    // layer 3
    k_agg256_bf<<<Nn / 4, 256, 0, stream>>>((const uint4*)hB, offs, srcs, invc, (uint4*)meanb);
    k_gemm_mfma<256, false><<<gb, 256, 0, stream>>>(meanb, hB, W3f, b3, g3, bt3, hA, Nn);
    // layer 4
    k_agg256_bf<<<Nn / 4, 256, 0, stream>>>((const uint4*)hA, offs, srcs, invc, (uint4*)meanb);
    k_gemm_mfma<128, true><<<gb, 256, 0, stream>>>(meanb, hA, W4f, b4, g4, bt4, hOut, Nn);
    // pool
    k_pool<<<Bb, 1024, 0, stream>>>(hOut, boff, out);
}